// Round 1
// baseline (387.339 us; speedup 1.0000x reference)
//
#include <hip/hip_runtime.h>
#include <stdint.h>

typedef __bf16 bf16;
typedef _Float16 f16;
typedef __bf16 bf16x8 __attribute__((ext_vector_type(8)));
typedef __bf16 bf16x4 __attribute__((ext_vector_type(4)));
typedef float f32x4 __attribute__((ext_vector_type(4)));
typedef _Float16 f16x4 __attribute__((ext_vector_type(4)));

#define NSEQ 1032
#define BATCH 8
#define NHEADS 12
#define HD 64
#define CDIM 768
#define MROWS (BATCH * NSEQ)   // 8256
#define PREFIX 8
#define BQ_ROWS 1152
#define BK_COLS 1088
// sqrt(0.125 * log2(e)) : folds both the hd^-0.5 attn scale and the
// exp->exp2 conversion into the K operand (applied to both sides of K.K^T).
#define KSCALE 0.42466090f

__device__ __forceinline__ unsigned short f2bf_rne(float f) {
    union { float f; uint32_t u; } v; v.f = f;
    uint32_t u = v.u;
    return (unsigned short)((u + 0x7fffu + ((u >> 16) & 1u)) >> 16);
}

__device__ __forceinline__ void gload_lds16(const bf16* g, bf16* l) {
    __builtin_amdgcn_global_load_lds(
        (const __attribute__((address_space(1))) void*)g,
        (__attribute__((address_space(3))) void*)l, 16, 0, 0);
}

__device__ __forceinline__ void cast4(const float* src, bf16* dst, int i) {
    float4 f = ((const float4*)src)[i];
    ushort4 o;
    o.x = f2bf_rne(f.x); o.y = f2bf_rne(f.y);
    o.z = f2bf_rne(f.z); o.w = f2bf_rne(f.w);
    ((ushort4*)dst)[i] = o;
}

// Fused prep: fp16 bias table (pre-multiplied by log2e) + x/qkv_w(kv)/proj_w casts.
__global__ void prep_kernel(const float* __restrict__ x,
                            const float* __restrict__ wkv,
                            const float* __restrict__ pw,
                            bf16* __restrict__ x_bf, bf16* __restrict__ wkv_bf,
                            bf16* __restrict__ pw_bf, f16* __restrict__ Bias) {
    const int N0 = BQ_ROWS * BK_COLS;
    const int N1 = MROWS * CDIM / 4;
    const int N2 = 2 * CDIM * CDIM / 4;
    const int N3 = CDIM * CDIM / 4;
    int i = blockIdx.x * blockDim.x + threadIdx.x;
    if (i < N0) {
        int q = i / BK_COLS, k = i % BK_COLS;
        float v;
        if (k >= NSEQ) v = -65504.f;   // exp2 -> 0 after adding bounded S
        else if (q < PREFIX || q >= NSEQ || k < PREFIX) v = 0.f;
        else {
            int rp = q - PREFIX, cp = k - PREFIX;
            int d1 = (rp >> 5) - (cp >> 5);
            int d2 = (rp & 31) - (cp & 31);
            v = 1.44269504f * __expf(-0.02f * (float)(d1 * d1 + d2 * d2));
        }
        Bias[i] = (f16)v;
        return;
    }
    i -= N0;
    if (i < N1) { cast4(x, x_bf, i); return; }
    i -= N1;
    if (i < N2) { cast4(wkv, wkv_bf, i); return; }
    i -= N2;
    if (i < N3) { cast4(pw, pw_bf, i); }
}

// NT GEMM, m97-style DMA staging.
// EPI=0: fp32 out. EPI=1: n<768 -> K' (scaled KSCALE) [B,H,s,d];
//                         n>=768 -> V^T layout [B,H,d,s] (d-major rows).
template<int EPI>
__global__ __launch_bounds__(256) void gemm_nt(
    const bf16* __restrict__ A, const bf16* __restrict__ B,
    const float* __restrict__ bias,
    float* __restrict__ Cout, bf16* __restrict__ Kout, bf16* __restrict__ Vout,
    int M, int N, int K)
{
    __shared__ bf16 sA[128 * 32];
    __shared__ bf16 sB[128 * 32];
    const int t = threadIdx.x;
    const int w = t >> 6;
    const int l = t & 63;
    const int quad = l >> 4;
    const int l15 = l & 15;
    const int wy = w >> 1, wx = w & 1;
    const int m0 = blockIdx.y * 128;
    const int n0 = blockIdx.x * 128;
    const int co = (quad ^ ((l15 >> 1) & 3)) * 8;

    int r0 = t >> 2,          c0 = (t & 3) ^ ((r0 >> 1) & 3);
    int r1 = (t + 256) >> 2,  c1 = ((t + 256) & 3) ^ ((r1 >> 1) & 3);
    int ra0 = m0 + r0; if (ra0 >= M) ra0 = M - 1;
    int ra1 = m0 + r1; if (ra1 >= M) ra1 = M - 1;
    const bf16* gA0 = A + (size_t)ra0 * K + c0 * 8;
    const bf16* gA1 = A + (size_t)ra1 * K + c1 * 8;
    const bf16* gB0 = B + (size_t)(n0 + r0) * K + c0 * 8;
    const bf16* gB1 = B + (size_t)(n0 + r1) * K + c1 * 8;
    bf16* dA0 = &sA[(size_t)(w * 64) * 8];
    bf16* dA1 = &sA[(size_t)(256 + w * 64) * 8];
    bf16* dB0 = &sB[(size_t)(w * 64) * 8];
    bf16* dB1 = &sB[(size_t)(256 + w * 64) * 8];

    f32x4 acc[4][4] = {};

    for (int k0 = 0; k0 < K; k0 += 32) {
        __syncthreads();
        gload_lds16(gA0, dA0); gload_lds16(gA1, dA1);
        gload_lds16(gB0, dB0); gload_lds16(gB1, dB1);
        gA0 += 32; gA1 += 32; gB0 += 32; gB1 += 32;
        __syncthreads();
        bf16x8 af[4], bq[4];
        #pragma unroll
        for (int mt = 0; mt < 4; ++mt)
            af[mt] = *(const bf16x8*)&sA[(wy*64 + mt*16 + l15) * 32 + co];
        #pragma unroll
        for (int nt = 0; nt < 4; ++nt)
            bq[nt] = *(const bf16x8*)&sB[(wx*64 + nt*16 + l15) * 32 + co];
        #pragma unroll
        for (int mt = 0; mt < 4; ++mt)
            #pragma unroll
            for (int nt = 0; nt < 4; ++nt)
                acc[mt][nt] = __builtin_amdgcn_mfma_f32_16x16x32_bf16(af[mt], bq[nt], acc[mt][nt], 0, 0, 0);
    }

    #pragma unroll
    for (int mt = 0; mt < 4; ++mt) {
        #pragma unroll
        for (int r = 0; r < 4; ++r) {
            int m = m0 + wy*64 + mt*16 + quad*4 + r;
            if (m >= M) continue;
            #pragma unroll
            for (int nt = 0; nt < 4; ++nt) {
                int n = n0 + wx*64 + nt*16 + l15;
                float v = acc[mt][nt][r] + bias[n];
                if (EPI == 0) {
                    Cout[(size_t)m * N + n] = v;
                } else {
                    int b = m / NSEQ, s = m % NSEQ;
                    if (n < CDIM) {
                        int h = n >> 6, d = n & 63;
                        Kout[(((size_t)(b*NHEADS + h))*NSEQ + s)*HD + d] = (bf16)(v * KSCALE);
                    } else {
                        int n2 = n - CDIM;
                        int h = n2 >> 6, d = n2 & 63;
                        // V transposed: row = d, col = s  (contiguous in s)
                        Vout[(((size_t)(b*NHEADS + h))*HD + d)*NSEQ + s] = (bf16)v;
                    }
                }
            }
        }
    }
}

// Attention, barrier-free: 4 waves x 32 q-rows. K A-frags and V^T B-frags
// are read directly from global (L1-resident tiles, coalesced 16B/lane).
// Only LDS use is the wave-private sP repack (f32 S^T -> bf16 P A-frags)
// and the wave-private row-sum redistribute. Zero __syncthreads.
__global__ __launch_bounds__(256, 4) void attn_kernel(
    const bf16* __restrict__ Kbuf, const bf16* __restrict__ VTbuf,
    const f16* __restrict__ Bias, bf16* __restrict__ Hout)
{
    const int bh = blockIdx.x;                  // bh-major: XCD locality
    const int b = bh / NHEADS, h = bh % NHEADS;
    const int q0 = blockIdx.y * 128;
    const bf16* Kh  = Kbuf  + (size_t)bh * NSEQ * HD;   // [s][d]
    const bf16* VTh = VTbuf + (size_t)bh * NSEQ * HD;   // [d][s]

    __shared__ bf16 sP[128 * 64];
    __shared__ float sL[128];

    const int t = threadIdx.x;
    const int w = t >> 6, l = t & 63, quad = l >> 4, l15 = l & 15;
    const int sw = l15 & 7;

    // Q fragments (B-operand), 2 x 16 query rows per wave; queries = keys here.
    bf16x8 qf[2][2];
    int qrow[2];
    #pragma unroll
    for (int qh = 0; qh < 2; ++qh) {
        qrow[qh] = q0 + w*32 + qh*16 + l15;
        int row = qrow[qh] > NSEQ - 1 ? NSEQ - 1 : qrow[qh];
        #pragma unroll
        for (int ks = 0; ks < 2; ++ks)
            qf[qh][ks] = *(const bf16x8*)&Kh[(size_t)row * HD + ks*32 + quad*8];
    }

    f32x4 Oacc[2][4] = {};
    float ps[2] = {0.f, 0.f};
    const int sPr0 = (w*32 + l15) * 64;

    for (int j0 = 0; j0 < NSEQ; j0 += 64) {
        // S^T accumulators init from fp16 bias table (already *log2e)
        f32x4 sacc[2][4];
        #pragma unroll
        for (int qh = 0; qh < 2; ++qh)
            #pragma unroll
            for (int kt = 0; kt < 4; ++kt) {
                f16x4 bb = __builtin_nontemporal_load(
                    (const f16x4*)&Bias[(size_t)qrow[qh] * BK_COLS + j0 + kt*16 + quad*4]);
                sacc[qh][kt] = (f32x4){(float)bb.x, (float)bb.y, (float)bb.z, (float)bb.w};
            }

        // S^T += K_tile * Q^T ; K A-frags straight from global (L1)
        #pragma unroll
        for (int ks = 0; ks < 2; ++ks) {
            bf16x8 af[4];
            #pragma unroll
            for (int kt = 0; kt < 4; ++kt) {
                int kr = j0 + kt*16 + l15;
                if (kr > NSEQ - 1) kr = NSEQ - 1;
                af[kt] = *(const bf16x8*)&Kh[(size_t)kr * HD + ks*32 + quad*8];
            }
            __builtin_amdgcn_s_setprio(1);
            #pragma unroll
            for (int qh = 0; qh < 2; ++qh)
                #pragma unroll
                for (int kt = 0; kt < 4; ++kt)
                    sacc[qh][kt] = __builtin_amdgcn_mfma_f32_16x16x32_bf16(
                        af[kt], qf[qh][ks], sacc[qh][kt], 0, 0, 0);
            __builtin_amdgcn_s_setprio(0);
        }

        // P = exp2(S^T); swizzled b64 stores into wave-private sP rows
        #pragma unroll
        for (int qh = 0; qh < 2; ++qh)
            #pragma unroll
            for (int kt = 0; kt < 4; ++kt) {
                float p0 = __builtin_exp2f(sacc[qh][kt][0]);
                float p1 = __builtin_exp2f(sacc[qh][kt][1]);
                float p2 = __builtin_exp2f(sacc[qh][kt][2]);
                float p3 = __builtin_exp2f(sacc[qh][kt][3]);
                ps[qh] += (p0 + p1) + (p2 + p3);
                bf16x4 pv = { (bf16)p0, (bf16)p1, (bf16)p2, (bf16)p3 };
                int g = (kt*2 + (quad >> 1)) ^ sw;
                *(bf16x4*)&sP[sPr0 + qh*1024 + g*8 + (quad & 1)*4] = pv;
            }

        // O += P V ; V^T B-frags straight from global (L1)
        #pragma unroll
        for (int ks = 0; ks < 2; ++ks) {
            int jc = j0 + ks*32 + quad*8;
            if (jc > NSEQ - 8) jc = NSEQ - 8;   // P=0 there, values harmless
            bf16x8 bv[4];
            #pragma unroll
            for (int dt = 0; dt < 4; ++dt)
                bv[dt] = *(const bf16x8*)&VTh[(size_t)(dt*16 + l15) * NSEQ + jc];
            __builtin_amdgcn_s_setprio(1);
            #pragma unroll
            for (int qh = 0; qh < 2; ++qh) {
                bf16x8 ap = *(const bf16x8*)&sP[sPr0 + qh*1024 + (((ks*4 + quad) ^ sw) * 8)];
                #pragma unroll
                for (int dt = 0; dt < 4; ++dt)
                    Oacc[qh][dt] = __builtin_amdgcn_mfma_f32_16x16x32_bf16(
                        ap, bv[dt], Oacc[qh][dt], 0, 0, 0);
            }
            __builtin_amdgcn_s_setprio(0);
        }
    }

    // row sums: reduce across quads, redistribute via wave-private sL rows
    #pragma unroll
    for (int qh = 0; qh < 2; ++qh) {
        float s = ps[qh];
        s += __shfl_xor(s, 16, 64);
        s += __shfl_xor(s, 32, 64);
        if (l < 16) sL[w*32 + qh*16 + l] = s;
    }

    #pragma unroll
    for (int qh = 0; qh < 2; ++qh)
        #pragma unroll
        for (int r = 0; r < 4; ++r) {
            int g = q0 + w*32 + qh*16 + quad*4 + r;
            if (g >= NSEQ) continue;
            float inv = 1.f / sL[w*32 + qh*16 + quad*4 + r];
            size_t base = ((size_t)(b * NSEQ) + g) * CDIM + h * HD;
            #pragma unroll
            for (int dt = 0; dt < 4; ++dt)
                Hout[base + dt*16 + l15] = (bf16)(Oacc[qh][dt][r] * inv);
        }
}

extern "C" void kernel_launch(void* const* d_in, const int* in_sizes, int n_in,
                              void* d_out, int out_size, void* d_ws, size_t ws_size,
                              hipStream_t stream) {
    const float* x      = (const float*)d_in[0];
    const float* qkv_w  = (const float*)d_in[1];
    const float* qkv_b  = (const float*)d_in[2];
    const float* proj_w = (const float*)d_in[3];
    const float* proj_b = (const float*)d_in[4];
    float* out = (float*)d_out;

    char* ws = (char*)d_ws;
    const size_t XBF_BYTES   = (size_t)MROWS * CDIM * 2;
    const size_t WKV_BYTES   = (size_t)2 * CDIM * CDIM * 2;
    const size_t PW_BYTES    = (size_t)CDIM * CDIM * 2;
    const size_t KBF_BYTES   = (size_t)BATCH * NHEADS * NSEQ * HD * 2;

    bf16* x_bf   = (bf16*)ws;
    bf16* wkv_bf = (bf16*)(ws + XBF_BYTES);
    bf16* pw_bf  = (bf16*)(ws + XBF_BYTES + WKV_BYTES);
    bf16* k_bf   = (bf16*)(ws + XBF_BYTES + WKV_BYTES + PW_BYTES);
    bf16* vt_bf  = (bf16*)(ws + XBF_BYTES + WKV_BYTES + PW_BYTES + KBF_BYTES);
    f16*  bias_t = (f16*)(ws + XBF_BYTES + WKV_BYTES + PW_BYTES + KBF_BYTES + KBF_BYTES);

    // fused prep: fp16 bias table + all casts
    {
        int total = BQ_ROWS * BK_COLS + MROWS * CDIM / 4
                  + 2 * CDIM * CDIM / 4 + CDIM * CDIM / 4;
        prep_kernel<<<dim3((total + 255) / 256), dim3(256), 0, stream>>>(
            x, qkv_w + (size_t)CDIM * CDIM, proj_w, x_bf, wkv_bf, pw_bf, bias_t);
    }

    // qkv GEMM (k & v only): M=8256, N=1536, K=768 ; writes K' and V^T
    {
        dim3 grid(1536 / 128, (MROWS + 127) / 128);
        gemm_nt<1><<<grid, dim3(256), 0, stream>>>(x_bf, wkv_bf, qkv_b + CDIM,
                                                   nullptr, k_bf, vt_bf,
                                                   MROWS, 1536, CDIM);
    }

    // attention -> hidden (reuse x_bf buffer); grid (bh, qtile)
    {
        dim3 grid(BATCH * NHEADS, (NSEQ + 127) / 128);
        attn_kernel<<<grid, dim3(256), 0, stream>>>(k_bf, vt_bf, bias_t, x_bf);
    }

    // proj GEMM: out = hidden @ proj_w^T + proj_b, fp32 out
    {
        dim3 grid(CDIM / 128, (MROWS + 127) / 128);
        gemm_nt<0><<<grid, dim3(256), 0, stream>>>(x_bf, pw_bf, proj_b,
                                                   out, nullptr, nullptr,
                                                   MROWS, CDIM, CDIM);
    }
}

// Round 2
// 348.448 us; speedup vs baseline: 1.1116x; 1.1116x over previous
//
#include <hip/hip_runtime.h>
#include <stdint.h>

typedef __bf16 bf16;
typedef _Float16 f16;
typedef __bf16 bf16x8 __attribute__((ext_vector_type(8)));
typedef __bf16 bf16x4 __attribute__((ext_vector_type(4)));
typedef float f32x4 __attribute__((ext_vector_type(4)));
typedef _Float16 f16x4 __attribute__((ext_vector_type(4)));

#define NSEQ 1032
#define BATCH 8
#define NHEADS 12
#define HD 64
#define CDIM 768
#define MROWS (BATCH * NSEQ)   // 8256
#define PREFIX 8
#define BQ_ROWS 1152
#define BK_COLS 1088
// sqrt(0.125 * log2(e)) : folds hd^-0.5 and exp->exp2 into K (both sides of K.K^T).
#define KSCALE 0.42466090f

__device__ __forceinline__ unsigned short f2bf_rne(float f) {
    union { float f; uint32_t u; } v; v.f = f;
    uint32_t u = v.u;
    return (unsigned short)((u + 0x7fffu + ((u >> 16) & 1u)) >> 16);
}

__device__ __forceinline__ void gload_lds16(const bf16* g, bf16* l) {
    __builtin_amdgcn_global_load_lds(
        (const __attribute__((address_space(1))) void*)g,
        (__attribute__((address_space(3))) void*)l, 16, 0, 0);
}

__device__ __forceinline__ void cast4(const float* src, bf16* dst, int i) {
    float4 f = ((const float4*)src)[i];
    ushort4 o;
    o.x = f2bf_rne(f.x); o.y = f2bf_rne(f.y);
    o.z = f2bf_rne(f.z); o.w = f2bf_rne(f.w);
    ((ushort4*)dst)[i] = o;
}

// Raw barrier: drains LDS ops only; global prefetch loads stay in flight
// (unlike __syncthreads, which emits s_waitcnt vmcnt(0)).
__device__ __forceinline__ void bar() {
    __builtin_amdgcn_sched_barrier(0);
    asm volatile("s_waitcnt lgkmcnt(0)" ::: "memory");
    __builtin_amdgcn_s_barrier();
    __builtin_amdgcn_sched_barrier(0);
}

// Fused prep: fp16 bias table (pre-multiplied by log2e) + x/qkv_w(kv)/proj_w casts.
__global__ void prep_kernel(const float* __restrict__ x,
                            const float* __restrict__ wkv,
                            const float* __restrict__ pw,
                            bf16* __restrict__ x_bf, bf16* __restrict__ wkv_bf,
                            bf16* __restrict__ pw_bf, f16* __restrict__ Bias) {
    const int N0 = BQ_ROWS * BK_COLS;
    const int N1 = MROWS * CDIM / 4;
    const int N2 = 2 * CDIM * CDIM / 4;
    const int N3 = CDIM * CDIM / 4;
    int i = blockIdx.x * blockDim.x + threadIdx.x;
    if (i < N0) {
        int q = i / BK_COLS, k = i % BK_COLS;
        float v;
        if (k >= NSEQ) v = -65504.f;   // exp2 -> 0
        else if (q < PREFIX || q >= NSEQ || k < PREFIX) v = 0.f;
        else {
            int rp = q - PREFIX, cp = k - PREFIX;
            int d1 = (rp >> 5) - (cp >> 5);
            int d2 = (rp & 31) - (cp & 31);
            v = 1.44269504f * __expf(-0.02f * (float)(d1 * d1 + d2 * d2));
        }
        Bias[i] = (f16)v;
        return;
    }
    i -= N0;
    if (i < N1) { cast4(x, x_bf, i); return; }
    i -= N1;
    if (i < N2) { cast4(wkv, wkv_bf, i); return; }
    i -= N2;
    if (i < N3) { cast4(pw, pw_bf, i); }
}

// NT GEMM, m97-style DMA staging.
// EPI=0: fp32 out. EPI=1: n<768 -> K' (scaled KSCALE) [B,H,s,d];
//                         n>=768 -> V^T layout [B,H,d,s], grouped bf16x4 stores.
template<int EPI>
__global__ __launch_bounds__(256) void gemm_nt(
    const bf16* __restrict__ A, const bf16* __restrict__ B,
    const float* __restrict__ bias,
    float* __restrict__ Cout, bf16* __restrict__ Kout, bf16* __restrict__ Vout,
    int M, int N, int K)
{
    __shared__ bf16 sA[128 * 32];
    __shared__ bf16 sB[128 * 32];
    const int t = threadIdx.x;
    const int w = t >> 6;
    const int l = t & 63;
    const int quad = l >> 4;
    const int l15 = l & 15;
    const int wy = w >> 1, wx = w & 1;
    const int m0 = blockIdx.y * 128;
    const int n0 = blockIdx.x * 128;
    const int co = (quad ^ ((l15 >> 1) & 3)) * 8;

    int r0 = t >> 2,          c0 = (t & 3) ^ ((r0 >> 1) & 3);
    int r1 = (t + 256) >> 2,  c1 = ((t + 256) & 3) ^ ((r1 >> 1) & 3);
    int ra0 = m0 + r0; if (ra0 >= M) ra0 = M - 1;
    int ra1 = m0 + r1; if (ra1 >= M) ra1 = M - 1;
    const bf16* gA0 = A + (size_t)ra0 * K + c0 * 8;
    const bf16* gA1 = A + (size_t)ra1 * K + c1 * 8;
    const bf16* gB0 = B + (size_t)(n0 + r0) * K + c0 * 8;
    const bf16* gB1 = B + (size_t)(n0 + r1) * K + c1 * 8;
    bf16* dA0 = &sA[(size_t)(w * 64) * 8];
    bf16* dA1 = &sA[(size_t)(256 + w * 64) * 8];
    bf16* dB0 = &sB[(size_t)(w * 64) * 8];
    bf16* dB1 = &sB[(size_t)(256 + w * 64) * 8];

    f32x4 acc[4][4] = {};

    for (int k0 = 0; k0 < K; k0 += 32) {
        __syncthreads();
        gload_lds16(gA0, dA0); gload_lds16(gA1, dA1);
        gload_lds16(gB0, dB0); gload_lds16(gB1, dB1);
        gA0 += 32; gA1 += 32; gB0 += 32; gB1 += 32;
        __syncthreads();
        bf16x8 af[4], bq[4];
        #pragma unroll
        for (int mt = 0; mt < 4; ++mt)
            af[mt] = *(const bf16x8*)&sA[(wy*64 + mt*16 + l15) * 32 + co];
        #pragma unroll
        for (int nt = 0; nt < 4; ++nt)
            bq[nt] = *(const bf16x8*)&sB[(wx*64 + nt*16 + l15) * 32 + co];
        #pragma unroll
        for (int mt = 0; mt < 4; ++mt)
            #pragma unroll
            for (int nt = 0; nt < 4; ++nt)
                acc[mt][nt] = __builtin_amdgcn_mfma_f32_16x16x32_bf16(af[mt], bq[nt], acc[mt][nt], 0, 0, 0);
    }

    if (EPI == 0) {
        #pragma unroll
        for (int mt = 0; mt < 4; ++mt) {
            #pragma unroll
            for (int r = 0; r < 4; ++r) {
                int m = m0 + wy*64 + mt*16 + quad*4 + r;
                if (m >= M) continue;
                #pragma unroll
                for (int nt = 0; nt < 4; ++nt) {
                    int n = n0 + wx*64 + nt*16 + l15;
                    Cout[(size_t)m * N + n] = acc[mt][nt][r] + bias[n];
                }
            }
        }
    } else {
        #pragma unroll
        for (int mt = 0; mt < 4; ++mt) {
            int mb = m0 + wy*64 + mt*16 + quad*4;     // 4-aligned; group stays in one (b,s) run
            if (mb >= M) continue;
            int b = mb / NSEQ, s = mb % NSEQ;
            #pragma unroll
            for (int nt = 0; nt < 4; ++nt) {
                int n = n0 + wx*64 + nt*16 + l15;
                float bn = bias[n];
                if (n < CDIM) {
                    int h = n >> 6, d = n & 63;
                    bf16* kp = &Kout[(((size_t)(b*NHEADS + h))*NSEQ + s)*HD + d];
                    #pragma unroll
                    for (int r = 0; r < 4; ++r)
                        kp[(size_t)r * HD] = (bf16)((acc[mt][nt][r] + bn) * KSCALE);
                } else {
                    int n2 = n - CDIM;
                    int h = n2 >> 6, d = n2 & 63;
                    bf16x4 pv = { (bf16)(acc[mt][nt][0] + bn), (bf16)(acc[mt][nt][1] + bn),
                                  (bf16)(acc[mt][nt][2] + bn), (bf16)(acc[mt][nt][3] + bn) };
                    *(bf16x4*)&Vout[(((size_t)(b*NHEADS + h))*HD + d)*NSEQ + s] = pv;
                }
            }
        }
    }
}

// Attention: 4 waves x 32 q-rows. K and V^T tiles staged in LDS with XOR
// swizzle (chunk ^= row&7) -> conflict-free ds_read_b128/ds_write_b128.
// Register prefetch of next tile's K/V/bias; raw barriers keep those global
// loads in flight (no vmcnt drain). sP swizzled as before (wave-private).
__global__ __launch_bounds__(256, 4) void attn_kernel(
    const bf16* __restrict__ Kbuf, const bf16* __restrict__ VTbuf,
    const f16* __restrict__ Bias, bf16* __restrict__ Hout)
{
    const int bh = blockIdx.x;                  // bh-major: XCD locality
    const int b = bh / NHEADS, h = bh % NHEADS;
    const int q0 = blockIdx.y * 128;
    const bf16* Kh  = Kbuf  + (size_t)bh * NSEQ * HD;   // [s][d]
    const bf16* VTh = VTbuf + (size_t)bh * NSEQ * HD;   // [d][s]

    __shared__ bf16 sK[64 * 64];
    __shared__ bf16 sVT[64 * 64];
    __shared__ bf16 sP[128 * 64];
    __shared__ float sL[128];

    const int t = threadIdx.x;
    const int w = t >> 6, l = t & 63, quad = l >> 4, l15 = l & 15;
    const int sw = l15 & 7;

    // staging geometry: 2 chunks (16B) per thread per buffer
    const int r0 = t >> 3, c0 = t & 7;
    const int r1 = r0 + 32;
    bf16* dK0 = &sK [r0*64 + ((c0 ^ (r0 & 7)) << 3)];
    bf16* dK1 = &sK [r1*64 + ((c0 ^ (r1 & 7)) << 3)];
    bf16* dV0 = &sVT[r0*64 + ((c0 ^ (r0 & 7)) << 3)];
    bf16* dV1 = &sVT[r1*64 + ((c0 ^ (r1 & 7)) << 3)];

    // Q fragments (B-operand), 2 x 16 query rows per wave; queries = keys.
    bf16x8 qf[2][2];
    int qrow[2];
    #pragma unroll
    for (int qh = 0; qh < 2; ++qh) {
        qrow[qh] = q0 + w*32 + qh*16 + l15;
        int row = qrow[qh] > NSEQ - 1 ? NSEQ - 1 : qrow[qh];
        #pragma unroll
        for (int ks = 0; ks < 2; ++ks)
            qf[qh][ks] = *(const bf16x8*)&Kh[(size_t)row * HD + ks*32 + quad*8];
    }

    f32x4 Oacc[2][4] = {};
    float ps[2] = {0.f, 0.f};
    const int sPr0 = (w*32 + l15) * 64;

    uint4 kva, kvb, vva, vvb;
#define PREFETCH(J) do { \
        int ka_ = (J) + r0; if (ka_ > NSEQ-1) ka_ = NSEQ-1; \
        int kb_ = (J) + r1; if (kb_ > NSEQ-1) kb_ = NSEQ-1; \
        int ja_ = (J) + c0*8; if (ja_ > NSEQ-8) ja_ = NSEQ-8; \
        kva = *(const uint4*)&Kh [(size_t)ka_ * HD + c0*8]; \
        kvb = *(const uint4*)&Kh [(size_t)kb_ * HD + c0*8]; \
        vva = *(const uint4*)&VTh[(size_t)r0 * NSEQ + ja_]; \
        vvb = *(const uint4*)&VTh[(size_t)r1 * NSEQ + ja_]; \
    } while (0)

    PREFETCH(0);

    for (int j0 = 0; j0 < NSEQ; j0 += 64) {
        // stage current tile from prefetch regs (swizzled b128 writes)
        *(uint4*)dK0 = kva; *(uint4*)dK1 = kvb;
        *(uint4*)dV0 = vva; *(uint4*)dV1 = vvb;

        // issue next tile's global loads (stay in flight across barriers)
        int jn = j0 + 64; if (jn >= NSEQ) jn = 0;
        PREFETCH(jn);
        f16x4 bpf[2][4];
        #pragma unroll
        for (int qh = 0; qh < 2; ++qh)
            #pragma unroll
            for (int kt = 0; kt < 4; ++kt)
                bpf[qh][kt] = *(const f16x4*)&Bias[(size_t)qrow[qh] * BK_COLS + j0 + kt*16 + quad*4];

        bar();   // staged tile visible; prefetch still in flight

        f32x4 sacc[2][4];
        #pragma unroll
        for (int qh = 0; qh < 2; ++qh)
            #pragma unroll
            for (int kt = 0; kt < 4; ++kt)
                sacc[qh][kt] = (f32x4){(float)bpf[qh][kt].x, (float)bpf[qh][kt].y,
                                       (float)bpf[qh][kt].z, (float)bpf[qh][kt].w};

        // S^T += K_tile * Q^T
        #pragma unroll
        for (int ks = 0; ks < 2; ++ks) {
            bf16x8 af[4];
            #pragma unroll
            for (int kt = 0; kt < 4; ++kt) {
                int row = kt*16 + l15;
                af[kt] = *(const bf16x8*)&sK[row*64 + (((ks*4 + quad) ^ sw) << 3)];
            }
            __builtin_amdgcn_s_setprio(1);
            #pragma unroll
            for (int qh = 0; qh < 2; ++qh)
                #pragma unroll
                for (int kt = 0; kt < 4; ++kt)
                    sacc[qh][kt] = __builtin_amdgcn_mfma_f32_16x16x32_bf16(
                        af[kt], qf[qh][ks], sacc[qh][kt], 0, 0, 0);
            __builtin_amdgcn_s_setprio(0);
        }

        // P = exp2(S^T); swizzled b64 stores into wave-private sP rows
        #pragma unroll
        for (int qh = 0; qh < 2; ++qh)
            #pragma unroll
            for (int kt = 0; kt < 4; ++kt) {
                float p0 = __builtin_exp2f(sacc[qh][kt][0]);
                float p1 = __builtin_exp2f(sacc[qh][kt][1]);
                float p2 = __builtin_exp2f(sacc[qh][kt][2]);
                float p3 = __builtin_exp2f(sacc[qh][kt][3]);
                ps[qh] += (p0 + p1) + (p2 + p3);
                bf16x4 pv = { (bf16)p0, (bf16)p1, (bf16)p2, (bf16)p3 };
                int g = (kt*2 + (quad >> 1)) ^ sw;
                *(bf16x4*)&sP[sPr0 + qh*1024 + g*8 + (quad & 1)*4] = pv;
            }

        // O += P V
        #pragma unroll
        for (int ks = 0; ks < 2; ++ks) {
            bf16x8 bv[4];
            #pragma unroll
            for (int dt = 0; dt < 4; ++dt) {
                int row = dt*16 + l15;
                bv[dt] = *(const bf16x8*)&sVT[row*64 + (((ks*4 + quad) ^ sw) << 3)];
            }
            __builtin_amdgcn_s_setprio(1);
            #pragma unroll
            for (int qh = 0; qh < 2; ++qh) {
                bf16x8 ap = *(const bf16x8*)&sP[sPr0 + qh*1024 + (((ks*4 + quad) ^ sw) * 8)];
                #pragma unroll
                for (int dt = 0; dt < 4; ++dt)
                    Oacc[qh][dt] = __builtin_amdgcn_mfma_f32_16x16x32_bf16(
                        ap, bv[dt], Oacc[qh][dt], 0, 0, 0);
            }
            __builtin_amdgcn_s_setprio(0);
        }

        bar();   // all reads of sK/sVT done; next iter may overwrite
    }
#undef PREFETCH

    // row sums: reduce across quads, redistribute via wave-private sL rows
    #pragma unroll
    for (int qh = 0; qh < 2; ++qh) {
        float s = ps[qh];
        s += __shfl_xor(s, 16, 64);
        s += __shfl_xor(s, 32, 64);
        if (l < 16) sL[w*32 + qh*16 + l] = s;
    }

    #pragma unroll
    for (int qh = 0; qh < 2; ++qh)
        #pragma unroll
        for (int r = 0; r < 4; ++r) {
            int g = q0 + w*32 + qh*16 + quad*4 + r;
            if (g >= NSEQ) continue;
            float inv = 1.f / sL[w*32 + qh*16 + quad*4 + r];
            size_t base = ((size_t)(b * NSEQ) + g) * CDIM + h * HD;
            #pragma unroll
            for (int dt = 0; dt < 4; ++dt)
                Hout[base + dt*16 + l15] = (bf16)(Oacc[qh][dt][r] * inv);
        }
}

extern "C" void kernel_launch(void* const* d_in, const int* in_sizes, int n_in,
                              void* d_out, int out_size, void* d_ws, size_t ws_size,
                              hipStream_t stream) {
    const float* x      = (const float*)d_in[0];
    const float* qkv_w  = (const float*)d_in[1];
    const float* qkv_b  = (const float*)d_in[2];
    const float* proj_w = (const float*)d_in[3];
    const float* proj_b = (const float*)d_in[4];
    float* out = (float*)d_out;

    char* ws = (char*)d_ws;
    const size_t XBF_BYTES   = (size_t)MROWS * CDIM * 2;
    const size_t WKV_BYTES   = (size_t)2 * CDIM * CDIM * 2;
    const size_t PW_BYTES    = (size_t)CDIM * CDIM * 2;
    const size_t KBF_BYTES   = (size_t)BATCH * NHEADS * NSEQ * HD * 2;

    bf16* x_bf   = (bf16*)ws;
    bf16* wkv_bf = (bf16*)(ws + XBF_BYTES);
    bf16* pw_bf  = (bf16*)(ws + XBF_BYTES + WKV_BYTES);
    bf16* k_bf   = (bf16*)(ws + XBF_BYTES + WKV_BYTES + PW_BYTES);
    bf16* vt_bf  = (bf16*)(ws + XBF_BYTES + WKV_BYTES + PW_BYTES + KBF_BYTES);
    f16*  bias_t = (f16*)(ws + XBF_BYTES + WKV_BYTES + PW_BYTES + KBF_BYTES + KBF_BYTES);

    // fused prep: fp16 bias table + all casts
    {
        int total = BQ_ROWS * BK_COLS + MROWS * CDIM / 4
                  + 2 * CDIM * CDIM / 4 + CDIM * CDIM / 4;
        prep_kernel<<<dim3((total + 255) / 256), dim3(256), 0, stream>>>(
            x, qkv_w + (size_t)CDIM * CDIM, proj_w, x_bf, wkv_bf, pw_bf, bias_t);
    }

    // qkv GEMM (k & v only): M=8256, N=1536, K=768 ; writes K' and V^T
    {
        dim3 grid(1536 / 128, (MROWS + 127) / 128);
        gemm_nt<1><<<grid, dim3(256), 0, stream>>>(x_bf, wkv_bf, qkv_b + CDIM,
                                                   nullptr, k_bf, vt_bf,
                                                   MROWS, 1536, CDIM);
    }

    // attention -> hidden (reuse x_bf buffer); grid (bh, qtile)
    {
        dim3 grid(BATCH * NHEADS, (NSEQ + 127) / 128);
        attn_kernel<<<grid, dim3(256), 0, stream>>>(k_bf, vt_bf, bias_t, x_bf);
    }

    // proj GEMM: out = hidden @ proj_w^T + proj_b, fp32 out
    {
        dim3 grid(CDIM / 128, (MROWS + 127) / 128);
        gemm_nt<0><<<grid, dim3(256), 0, stream>>>(x_bf, pw_bf, proj_b,
                                                   out, nullptr, nullptr,
                                                   MROWS, CDIM, CDIM);
    }
}

// Round 3
// 262.390 us; speedup vs baseline: 1.4762x; 1.3280x over previous
//
#include <hip/hip_runtime.h>
#include <stdint.h>

typedef __bf16 bf16;
typedef _Float16 f16;
typedef __bf16 bf16x8 __attribute__((ext_vector_type(8)));
typedef __bf16 bf16x4 __attribute__((ext_vector_type(4)));
typedef float f32x4 __attribute__((ext_vector_type(4)));
typedef _Float16 f16x4 __attribute__((ext_vector_type(4)));

#define NSEQ 1032
#define BATCH 8
#define NHEADS 12
#define HD 64
#define CDIM 768
#define MROWS (BATCH * NSEQ)   // 8256
#define PREFIX 8
#define BQ_ROWS 1152
#define BK_COLS 1088
// sqrt(0.125 * log2(e)) : folds hd^-0.5 and exp->exp2 into K (both sides of K.K^T).
#define KSCALE 0.42466090f

__device__ __forceinline__ unsigned short f2bf_rne(float f) {
    union { float f; uint32_t u; } v; v.f = f;
    uint32_t u = v.u;
    return (unsigned short)((u + 0x7fffu + ((u >> 16) & 1u)) >> 16);
}

__device__ __forceinline__ void gload_lds16(const bf16* g, bf16* l) {
    __builtin_amdgcn_global_load_lds(
        (const __attribute__((address_space(1))) void*)g,
        (__attribute__((address_space(3))) void*)l, 16, 0, 0);
}

__device__ __forceinline__ void cast4(const float* src, bf16* dst, int i) {
    float4 f = ((const float4*)src)[i];
    ushort4 o;
    o.x = f2bf_rne(f.x); o.y = f2bf_rne(f.y);
    o.z = f2bf_rne(f.z); o.w = f2bf_rne(f.w);
    ((ushort4*)dst)[i] = o;
}

// Raw barrier: drains LDS ops only; global prefetch loads stay in flight
// (unlike __syncthreads, which emits s_waitcnt vmcnt(0)). Plain memory
// fences (no sched_barrier) so the scheduler keeps freedom -> no register
// pressure blowup (round-2 lesson: sched_barrier(0) + VGPR cap = spills).
__device__ __forceinline__ void bar() {
    asm volatile("s_waitcnt lgkmcnt(0)" ::: "memory");
    __builtin_amdgcn_s_barrier();
    asm volatile("" ::: "memory");
}

// Fused prep: fp16 bias table (pre-multiplied by log2e) + x/qkv_w(kv)/proj_w casts.
__global__ void prep_kernel(const float* __restrict__ x,
                            const float* __restrict__ wkv,
                            const float* __restrict__ pw,
                            bf16* __restrict__ x_bf, bf16* __restrict__ wkv_bf,
                            bf16* __restrict__ pw_bf, f16* __restrict__ Bias) {
    const int N0 = BQ_ROWS * BK_COLS;
    const int N1 = MROWS * CDIM / 4;
    const int N2 = 2 * CDIM * CDIM / 4;
    const int N3 = CDIM * CDIM / 4;
    int i = blockIdx.x * blockDim.x + threadIdx.x;
    if (i < N0) {
        int q = i / BK_COLS, k = i % BK_COLS;
        float v;
        if (k >= NSEQ) v = -65504.f;   // exp2 -> 0
        else if (q < PREFIX || q >= NSEQ || k < PREFIX) v = 0.f;
        else {
            int rp = q - PREFIX, cp = k - PREFIX;
            int d1 = (rp >> 5) - (cp >> 5);
            int d2 = (rp & 31) - (cp & 31);
            v = 1.44269504f * __expf(-0.02f * (float)(d1 * d1 + d2 * d2));
        }
        Bias[i] = (f16)v;
        return;
    }
    i -= N0;
    if (i < N1) { cast4(x, x_bf, i); return; }
    i -= N1;
    if (i < N2) { cast4(wkv, wkv_bf, i); return; }
    i -= N2;
    if (i < N3) { cast4(pw, pw_bf, i); }
}

// NT GEMM, m97-style DMA staging.
// EPI=0: fp32 out. EPI=1: n<768 -> K' (scaled KSCALE) [B,H,s,d];
//                         n>=768 -> V^T layout [B,H,d,s], grouped bf16x4 stores.
template<int EPI>
__global__ __launch_bounds__(256) void gemm_nt(
    const bf16* __restrict__ A, const bf16* __restrict__ B,
    const float* __restrict__ bias,
    float* __restrict__ Cout, bf16* __restrict__ Kout, bf16* __restrict__ Vout,
    int M, int N, int K)
{
    __shared__ bf16 sA[128 * 32];
    __shared__ bf16 sB[128 * 32];
    const int t = threadIdx.x;
    const int w = t >> 6;
    const int l = t & 63;
    const int quad = l >> 4;
    const int l15 = l & 15;
    const int wy = w >> 1, wx = w & 1;
    const int m0 = blockIdx.y * 128;
    const int n0 = blockIdx.x * 128;
    const int co = (quad ^ ((l15 >> 1) & 3)) * 8;

    int r0 = t >> 2,          c0 = (t & 3) ^ ((r0 >> 1) & 3);
    int r1 = (t + 256) >> 2,  c1 = ((t + 256) & 3) ^ ((r1 >> 1) & 3);
    int ra0 = m0 + r0; if (ra0 >= M) ra0 = M - 1;
    int ra1 = m0 + r1; if (ra1 >= M) ra1 = M - 1;
    const bf16* gA0 = A + (size_t)ra0 * K + c0 * 8;
    const bf16* gA1 = A + (size_t)ra1 * K + c1 * 8;
    const bf16* gB0 = B + (size_t)(n0 + r0) * K + c0 * 8;
    const bf16* gB1 = B + (size_t)(n0 + r1) * K + c1 * 8;
    bf16* dA0 = &sA[(size_t)(w * 64) * 8];
    bf16* dA1 = &sA[(size_t)(256 + w * 64) * 8];
    bf16* dB0 = &sB[(size_t)(w * 64) * 8];
    bf16* dB1 = &sB[(size_t)(256 + w * 64) * 8];

    f32x4 acc[4][4] = {};

    for (int k0 = 0; k0 < K; k0 += 32) {
        __syncthreads();
        gload_lds16(gA0, dA0); gload_lds16(gA1, dA1);
        gload_lds16(gB0, dB0); gload_lds16(gB1, dB1);
        gA0 += 32; gA1 += 32; gB0 += 32; gB1 += 32;
        __syncthreads();
        bf16x8 af[4], bq[4];
        #pragma unroll
        for (int mt = 0; mt < 4; ++mt)
            af[mt] = *(const bf16x8*)&sA[(wy*64 + mt*16 + l15) * 32 + co];
        #pragma unroll
        for (int nt = 0; nt < 4; ++nt)
            bq[nt] = *(const bf16x8*)&sB[(wx*64 + nt*16 + l15) * 32 + co];
        #pragma unroll
        for (int mt = 0; mt < 4; ++mt)
            #pragma unroll
            for (int nt = 0; nt < 4; ++nt)
                acc[mt][nt] = __builtin_amdgcn_mfma_f32_16x16x32_bf16(af[mt], bq[nt], acc[mt][nt], 0, 0, 0);
    }

    if (EPI == 0) {
        #pragma unroll
        for (int mt = 0; mt < 4; ++mt) {
            #pragma unroll
            for (int r = 0; r < 4; ++r) {
                int m = m0 + wy*64 + mt*16 + quad*4 + r;
                if (m >= M) continue;
                #pragma unroll
                for (int nt = 0; nt < 4; ++nt) {
                    int n = n0 + wx*64 + nt*16 + l15;
                    Cout[(size_t)m * N + n] = acc[mt][nt][r] + bias[n];
                }
            }
        }
    } else {
        #pragma unroll
        for (int mt = 0; mt < 4; ++mt) {
            int mb = m0 + wy*64 + mt*16 + quad*4;     // 4-aligned; group stays in one (b,s) run
            if (mb >= M) continue;
            int b = mb / NSEQ, s = mb % NSEQ;
            #pragma unroll
            for (int nt = 0; nt < 4; ++nt) {
                int n = n0 + wx*64 + nt*16 + l15;
                float bn = bias[n];
                if (n < CDIM) {
                    int h = n >> 6, d = n & 63;
                    bf16* kp = &Kout[(((size_t)(b*NHEADS + h))*NSEQ + s)*HD + d];
                    #pragma unroll
                    for (int r = 0; r < 4; ++r)
                        kp[(size_t)r * HD] = (bf16)((acc[mt][nt][r] + bn) * KSCALE);
                } else {
                    int n2 = n - CDIM;
                    int h = n2 >> 6, d = n2 & 63;
                    bf16x4 pv = { (bf16)(acc[mt][nt][0] + bn), (bf16)(acc[mt][nt][1] + bn),
                                  (bf16)(acc[mt][nt][2] + bn), (bf16)(acc[mt][nt][3] + bn) };
                    *(bf16x4*)&Vout[(((size_t)(b*NHEADS + h))*HD + d)*NSEQ + s] = pv;
                }
            }
        }
    }
}

// Attention: 4 waves x 32 q-rows. K and V^T tiles staged in LDS with XOR
// swizzle (chunk ^= row&7) -> conflict-free ds_read_b128/ds_write_b128.
// Register prefetch of next tile's K/V; raw barriers keep those global
// loads in flight (no vmcnt drain). Bias loaded post-barrier (L2-resident,
// shared by all heads). No launch_bounds occupancy forcing (spill lesson).
__global__ __launch_bounds__(256) void attn_kernel(
    const bf16* __restrict__ Kbuf, const bf16* __restrict__ VTbuf,
    const f16* __restrict__ Bias, bf16* __restrict__ Hout)
{
    const int bh = blockIdx.x;                  // bh-major: XCD locality
    const int b = bh / NHEADS, h = bh % NHEADS;
    const int q0 = blockIdx.y * 128;
    const bf16* Kh  = Kbuf  + (size_t)bh * NSEQ * HD;   // [s][d]
    const bf16* VTh = VTbuf + (size_t)bh * NSEQ * HD;   // [d][s]

    __shared__ bf16 sK[64 * 64];
    __shared__ bf16 sVT[64 * 64];
    __shared__ bf16 sP[128 * 64];
    __shared__ float sL[128];

    const int t = threadIdx.x;
    const int w = t >> 6, l = t & 63, quad = l >> 4, l15 = l & 15;
    const int sw = l15 & 7;

    // staging geometry: 2 chunks (16B) per thread per buffer
    const int r0 = t >> 3, c0 = t & 7;
    const int r1 = r0 + 32;
    bf16* dK0 = &sK [r0*64 + ((c0 ^ (r0 & 7)) << 3)];
    bf16* dK1 = &sK [r1*64 + ((c0 ^ (r1 & 7)) << 3)];
    bf16* dV0 = &sVT[r0*64 + ((c0 ^ (r0 & 7)) << 3)];
    bf16* dV1 = &sVT[r1*64 + ((c0 ^ (r1 & 7)) << 3)];

    // Q fragments (B-operand), 2 x 16 query rows per wave; queries = keys.
    bf16x8 qf[2][2];
    int qrow[2];
    #pragma unroll
    for (int qh = 0; qh < 2; ++qh) {
        qrow[qh] = q0 + w*32 + qh*16 + l15;
        int row = qrow[qh] > NSEQ - 1 ? NSEQ - 1 : qrow[qh];
        #pragma unroll
        for (int ks = 0; ks < 2; ++ks)
            qf[qh][ks] = *(const bf16x8*)&Kh[(size_t)row * HD + ks*32 + quad*8];
    }

    f32x4 Oacc[2][4] = {};
    float ps[2] = {0.f, 0.f};
    const int sPr0 = (w*32 + l15) * 64;

    uint4 kva, kvb, vva, vvb;
#define PREFETCH(J) do { \
        int ka_ = (J) + r0; if (ka_ > NSEQ-1) ka_ = NSEQ-1; \
        int kb_ = (J) + r1; if (kb_ > NSEQ-1) kb_ = NSEQ-1; \
        int ja_ = (J) + c0*8; if (ja_ > NSEQ-8) ja_ = NSEQ-8; \
        kva = *(const uint4*)&Kh [(size_t)ka_ * HD + c0*8]; \
        kvb = *(const uint4*)&Kh [(size_t)kb_ * HD + c0*8]; \
        vva = *(const uint4*)&VTh[(size_t)r0 * NSEQ + ja_]; \
        vvb = *(const uint4*)&VTh[(size_t)r1 * NSEQ + ja_]; \
    } while (0)

    PREFETCH(0);

    for (int j0 = 0; j0 < NSEQ; j0 += 64) {
        // stage current tile from prefetch regs (swizzled b128 writes)
        *(uint4*)dK0 = kva; *(uint4*)dK1 = kvb;
        *(uint4*)dV0 = vva; *(uint4*)dV1 = vvb;

        // issue next tile's global loads (stay in flight across barriers)
        int jn = j0 + 64; if (jn >= NSEQ) jn = 0;
        PREFETCH(jn);

        bar();   // staged tile visible; prefetch still in flight

        // S^T accumulators init from fp16 bias table (L2-resident)
        f32x4 sacc[2][4];
        #pragma unroll
        for (int qh = 0; qh < 2; ++qh)
            #pragma unroll
            for (int kt = 0; kt < 4; ++kt) {
                f16x4 bb = *(const f16x4*)&Bias[(size_t)qrow[qh] * BK_COLS + j0 + kt*16 + quad*4];
                sacc[qh][kt] = (f32x4){(float)bb.x, (float)bb.y, (float)bb.z, (float)bb.w};
            }

        // S^T += K_tile * Q^T
        #pragma unroll
        for (int ks = 0; ks < 2; ++ks) {
            bf16x8 af[4];
            #pragma unroll
            for (int kt = 0; kt < 4; ++kt) {
                int row = kt*16 + l15;
                af[kt] = *(const bf16x8*)&sK[row*64 + (((ks*4 + quad) ^ sw) << 3)];
            }
            __builtin_amdgcn_s_setprio(1);
            #pragma unroll
            for (int qh = 0; qh < 2; ++qh)
                #pragma unroll
                for (int kt = 0; kt < 4; ++kt)
                    sacc[qh][kt] = __builtin_amdgcn_mfma_f32_16x16x32_bf16(
                        af[kt], qf[qh][ks], sacc[qh][kt], 0, 0, 0);
            __builtin_amdgcn_s_setprio(0);
        }

        // P = exp2(S^T); swizzled b64 stores into wave-private sP rows
        #pragma unroll
        for (int qh = 0; qh < 2; ++qh)
            #pragma unroll
            for (int kt = 0; kt < 4; ++kt) {
                float p0 = __builtin_exp2f(sacc[qh][kt][0]);
                float p1 = __builtin_exp2f(sacc[qh][kt][1]);
                float p2 = __builtin_exp2f(sacc[qh][kt][2]);
                float p3 = __builtin_exp2f(sacc[qh][kt][3]);
                ps[qh] += (p0 + p1) + (p2 + p3);
                bf16x4 pv = { (bf16)p0, (bf16)p1, (bf16)p2, (bf16)p3 };
                int g = (kt*2 + (quad >> 1)) ^ sw;
                *(bf16x4*)&sP[sPr0 + qh*1024 + g*8 + (quad & 1)*4] = pv;
            }

        // O += P V
        #pragma unroll
        for (int ks = 0; ks < 2; ++ks) {
            bf16x8 bv[4];
            #pragma unroll
            for (int dt = 0; dt < 4; ++dt) {
                int row = dt*16 + l15;
                bv[dt] = *(const bf16x8*)&sVT[row*64 + (((ks*4 + quad) ^ sw) << 3)];
            }
            __builtin_amdgcn_s_setprio(1);
            #pragma unroll
            for (int qh = 0; qh < 2; ++qh) {
                bf16x8 ap = *(const bf16x8*)&sP[sPr0 + qh*1024 + (((ks*4 + quad) ^ sw) * 8)];
                #pragma unroll
                for (int dt = 0; dt < 4; ++dt)
                    Oacc[qh][dt] = __builtin_amdgcn_mfma_f32_16x16x32_bf16(
                        ap, bv[dt], Oacc[qh][dt], 0, 0, 0);
            }
            __builtin_amdgcn_s_setprio(0);
        }

        bar();   // all reads of sK/sVT done; next iter may overwrite
    }
#undef PREFETCH

    // row sums: reduce across quads, redistribute via wave-private sL rows
    #pragma unroll
    for (int qh = 0; qh < 2; ++qh) {
        float s = ps[qh];
        s += __shfl_xor(s, 16, 64);
        s += __shfl_xor(s, 32, 64);
        if (l < 16) sL[w*32 + qh*16 + l] = s;
    }

    #pragma unroll
    for (int qh = 0; qh < 2; ++qh)
        #pragma unroll
        for (int r = 0; r < 4; ++r) {
            int g = q0 + w*32 + qh*16 + quad*4 + r;
            if (g >= NSEQ) continue;
            float inv = 1.f / sL[w*32 + qh*16 + quad*4 + r];
            size_t base = ((size_t)(b * NSEQ) + g) * CDIM + h * HD;
            #pragma unroll
            for (int dt = 0; dt < 4; ++dt)
                Hout[base + dt*16 + l15] = (bf16)(Oacc[qh][dt][r] * inv);
        }
}

extern "C" void kernel_launch(void* const* d_in, const int* in_sizes, int n_in,
                              void* d_out, int out_size, void* d_ws, size_t ws_size,
                              hipStream_t stream) {
    const float* x      = (const float*)d_in[0];
    const float* qkv_w  = (const float*)d_in[1];
    const float* qkv_b  = (const float*)d_in[2];
    const float* proj_w = (const float*)d_in[3];
    const float* proj_b = (const float*)d_in[4];
    float* out = (float*)d_out;

    char* ws = (char*)d_ws;
    const size_t XBF_BYTES   = (size_t)MROWS * CDIM * 2;
    const size_t WKV_BYTES   = (size_t)2 * CDIM * CDIM * 2;
    const size_t PW_BYTES    = (size_t)CDIM * CDIM * 2;
    const size_t KBF_BYTES   = (size_t)BATCH * NHEADS * NSEQ * HD * 2;

    bf16* x_bf   = (bf16*)ws;
    bf16* wkv_bf = (bf16*)(ws + XBF_BYTES);
    bf16* pw_bf  = (bf16*)(ws + XBF_BYTES + WKV_BYTES);
    bf16* k_bf   = (bf16*)(ws + XBF_BYTES + WKV_BYTES + PW_BYTES);
    bf16* vt_bf  = (bf16*)(ws + XBF_BYTES + WKV_BYTES + PW_BYTES + KBF_BYTES);
    f16*  bias_t = (f16*)(ws + XBF_BYTES + WKV_BYTES + PW_BYTES + KBF_BYTES + KBF_BYTES);

    // fused prep: fp16 bias table + all casts
    {
        int total = BQ_ROWS * BK_COLS + MROWS * CDIM / 4
                  + 2 * CDIM * CDIM / 4 + CDIM * CDIM / 4;
        prep_kernel<<<dim3((total + 255) / 256), dim3(256), 0, stream>>>(
            x, qkv_w + (size_t)CDIM * CDIM, proj_w, x_bf, wkv_bf, pw_bf, bias_t);
    }

    // qkv GEMM (k & v only): M=8256, N=1536, K=768 ; writes K' and V^T
    {
        dim3 grid(1536 / 128, (MROWS + 127) / 128);
        gemm_nt<1><<<grid, dim3(256), 0, stream>>>(x_bf, wkv_bf, qkv_b + CDIM,
                                                   nullptr, k_bf, vt_bf,
                                                   MROWS, 1536, CDIM);
    }

    // attention -> hidden (reuse x_bf buffer); grid (bh, qtile)
    {
        dim3 grid(BATCH * NHEADS, (NSEQ + 127) / 128);
        attn_kernel<<<grid, dim3(256), 0, stream>>>(k_bf, vt_bf, bias_t, x_bf);
    }

    // proj GEMM: out = hidden @ proj_w^T + proj_b, fp32 out
    {
        dim3 grid(CDIM / 128, (MROWS + 127) / 128);
        gemm_nt<0><<<grid, dim3(256), 0, stream>>>(x_bf, pw_bf, proj_b,
                                                   out, nullptr, nullptr,
                                                   MROWS, CDIM, CDIM);
    }
}

// Round 4
// 238.360 us; speedup vs baseline: 1.6250x; 1.1008x over previous
//
#include <hip/hip_runtime.h>
#include <stdint.h>

typedef __bf16 bf16;
typedef _Float16 f16;
typedef __bf16 bf16x8 __attribute__((ext_vector_type(8)));
typedef __bf16 bf16x4 __attribute__((ext_vector_type(4)));
typedef float f32x4 __attribute__((ext_vector_type(4)));
typedef _Float16 f16x4 __attribute__((ext_vector_type(4)));

#define NSEQ 1032
#define BATCH 8
#define NHEADS 12
#define HD 64
#define CDIM 768
#define MROWS (BATCH * NSEQ)   // 8256
#define PREFIX 8
#define NJT 17                 // j-tiles of 64 keys (covers 1088)
#define NQ16 72                // 16-row q groups (covers 1152)
// sqrt(0.125 * log2(e)) : folds hd^-0.5 and exp->exp2 into K (both sides of K.K^T).
#define KSCALE 0.42466090f

__device__ __forceinline__ unsigned short f2bf_rne(float f) {
    union { float f; uint32_t u; } v; v.f = f;
    uint32_t u = v.u;
    return (unsigned short)((u + 0x7fffu + ((u >> 16) & 1u)) >> 16);
}

__device__ __forceinline__ void gload_lds16(const bf16* g, bf16* l) {
    __builtin_amdgcn_global_load_lds(
        (const __attribute__((address_space(1))) void*)g,
        (__attribute__((address_space(3))) void*)l, 16, 0, 0);
}

__device__ __forceinline__ void cast4(const float* src, bf16* dst, int i) {
    float4 f = ((const float4*)src)[i];
    ushort4 o;
    o.x = f2bf_rne(f.x); o.y = f2bf_rne(f.y);
    o.z = f2bf_rne(f.z); o.w = f2bf_rne(f.w);
    ((ushort4*)dst)[i] = o;
}

// Raw barrier: drains LDS ops only; global prefetch loads stay in flight.
__device__ __forceinline__ void bar() {
    asm volatile("s_waitcnt lgkmcnt(0)" ::: "memory");
    __builtin_amdgcn_s_barrier();
    asm volatile("" ::: "memory");
}

// Fused prep: fragment-linear f16 bias table + x/qkv_w(kv)/proj_w casts.
// B2 layout: [q16][jt][kt][quad][l15][r] f16, value = log2e * gauss(q,k)
// with q = q16*16 + l15, k = jt*64 + kt*16 + quad*4 + r.
// A wave's per-(q16,jt,kt) fragment is then one coalesced b64 load per lane.
__global__ void prep_kernel(const float* __restrict__ x,
                            const float* __restrict__ wkv,
                            const float* __restrict__ pw,
                            bf16* __restrict__ x_bf, bf16* __restrict__ wkv_bf,
                            bf16* __restrict__ pw_bf, f16* __restrict__ Bias) {
    const int N0 = NQ16 * NJT * 1024;          // 1,253,376
    const int N1 = MROWS * CDIM / 4;
    const int N2 = 2 * CDIM * CDIM / 4;
    const int N3 = CDIM * CDIM / 4;
    int i = blockIdx.x * blockDim.x + threadIdx.x;
    if (i < N0) {
        int r    = i & 3;
        int l15  = (i >> 2) & 15;
        int quad = (i >> 6) & 3;
        int kt   = (i >> 8) & 3;
        int rest = i >> 10;                    // q16*NJT + jt
        int q16  = rest / NJT;
        int jt   = rest - q16 * NJT;
        int q = q16 * 16 + l15;
        int k = jt * 64 + kt * 16 + quad * 4 + r;
        float v;
        if (k >= NSEQ) v = -65504.f;           // exp2 -> 0
        else if (q < PREFIX || q >= NSEQ || k < PREFIX) v = 0.f;
        else {
            int rp = q - PREFIX, cp = k - PREFIX;
            int d1 = (rp >> 5) - (cp >> 5);
            int d2 = (rp & 31) - (cp & 31);
            v = 1.44269504f * __expf(-0.02f * (float)(d1 * d1 + d2 * d2));
        }
        Bias[i] = (f16)v;
        return;
    }
    i -= N0;
    if (i < N1) { cast4(x, x_bf, i); return; }
    i -= N1;
    if (i < N2) { cast4(wkv, wkv_bf, i); return; }
    i -= N2;
    if (i < N3) { cast4(pw, pw_bf, i); }
}

// NT GEMM, m97-style DMA staging.
// EPI=0: fp32 out. EPI=1: n<768 -> K' (scaled KSCALE) [B,H,s,d];
//                         n>=768 -> V^T layout [B,H,d,s], grouped bf16x4 stores.
template<int EPI>
__global__ __launch_bounds__(256) void gemm_nt(
    const bf16* __restrict__ A, const bf16* __restrict__ B,
    const float* __restrict__ bias,
    float* __restrict__ Cout, bf16* __restrict__ Kout, bf16* __restrict__ Vout,
    int M, int N, int K)
{
    __shared__ bf16 sA[128 * 32];
    __shared__ bf16 sB[128 * 32];
    const int t = threadIdx.x;
    const int w = t >> 6;
    const int l = t & 63;
    const int quad = l >> 4;
    const int l15 = l & 15;
    const int wy = w >> 1, wx = w & 1;
    const int m0 = blockIdx.y * 128;
    const int n0 = blockIdx.x * 128;
    const int co = (quad ^ ((l15 >> 1) & 3)) * 8;

    int r0 = t >> 2,          c0 = (t & 3) ^ ((r0 >> 1) & 3);
    int r1 = (t + 256) >> 2,  c1 = ((t + 256) & 3) ^ ((r1 >> 1) & 3);
    int ra0 = m0 + r0; if (ra0 >= M) ra0 = M - 1;
    int ra1 = m0 + r1; if (ra1 >= M) ra1 = M - 1;
    const bf16* gA0 = A + (size_t)ra0 * K + c0 * 8;
    const bf16* gA1 = A + (size_t)ra1 * K + c1 * 8;
    const bf16* gB0 = B + (size_t)(n0 + r0) * K + c0 * 8;
    const bf16* gB1 = B + (size_t)(n0 + r1) * K + c1 * 8;
    bf16* dA0 = &sA[(size_t)(w * 64) * 8];
    bf16* dA1 = &sA[(size_t)(256 + w * 64) * 8];
    bf16* dB0 = &sB[(size_t)(w * 64) * 8];
    bf16* dB1 = &sB[(size_t)(256 + w * 64) * 8];

    f32x4 acc[4][4] = {};

    for (int k0 = 0; k0 < K; k0 += 32) {
        __syncthreads();
        gload_lds16(gA0, dA0); gload_lds16(gA1, dA1);
        gload_lds16(gB0, dB0); gload_lds16(gB1, dB1);
        gA0 += 32; gA1 += 32; gB0 += 32; gB1 += 32;
        __syncthreads();
        bf16x8 af[4], bq[4];
        #pragma unroll
        for (int mt = 0; mt < 4; ++mt)
            af[mt] = *(const bf16x8*)&sA[(wy*64 + mt*16 + l15) * 32 + co];
        #pragma unroll
        for (int nt = 0; nt < 4; ++nt)
            bq[nt] = *(const bf16x8*)&sB[(wx*64 + nt*16 + l15) * 32 + co];
        #pragma unroll
        for (int mt = 0; mt < 4; ++mt)
            #pragma unroll
            for (int nt = 0; nt < 4; ++nt)
                acc[mt][nt] = __builtin_amdgcn_mfma_f32_16x16x32_bf16(af[mt], bq[nt], acc[mt][nt], 0, 0, 0);
    }

    if (EPI == 0) {
        #pragma unroll
        for (int mt = 0; mt < 4; ++mt) {
            #pragma unroll
            for (int r = 0; r < 4; ++r) {
                int m = m0 + wy*64 + mt*16 + quad*4 + r;
                if (m >= M) continue;
                #pragma unroll
                for (int nt = 0; nt < 4; ++nt) {
                    int n = n0 + wx*64 + nt*16 + l15;
                    Cout[(size_t)m * N + n] = acc[mt][nt][r] + bias[n];
                }
            }
        }
    } else {
        #pragma unroll
        for (int mt = 0; mt < 4; ++mt) {
            int mb = m0 + wy*64 + mt*16 + quad*4;     // 4-aligned; group stays in one (b,s) run
            if (mb >= M) continue;
            int b = mb / NSEQ, s = mb % NSEQ;
            #pragma unroll
            for (int nt = 0; nt < 4; ++nt) {
                int n = n0 + wx*64 + nt*16 + l15;
                float bn = bias[n];
                if (n < CDIM) {
                    int h = n >> 6, d = n & 63;
                    bf16* kp = &Kout[(((size_t)(b*NHEADS + h))*NSEQ + s)*HD + d];
                    #pragma unroll
                    for (int r = 0; r < 4; ++r)
                        kp[(size_t)r * HD] = (bf16)((acc[mt][nt][r] + bn) * KSCALE);
                } else {
                    int n2 = n - CDIM;
                    int h = n2 >> 6, d = n2 & 63;
                    bf16x4 pv = { (bf16)(acc[mt][nt][0] + bn), (bf16)(acc[mt][nt][1] + bn),
                                  (bf16)(acc[mt][nt][2] + bn), (bf16)(acc[mt][nt][3] + bn) };
                    *(bf16x4*)&Vout[(((size_t)(b*NHEADS + h))*HD + d)*NSEQ + s] = pv;
                }
            }
        }
    }
}

// Attention: 4 waves x 32 q-rows. Swizzled LDS staging of K and V^T
// (conflict-free b128), register prefetch of next tile's K/V and
// fragment-linear bias (coalesced b64, consumed pre-barrier into sacc),
// lgkm-only barriers keep global loads in flight.
__global__ __launch_bounds__(256) void attn_kernel(
    const bf16* __restrict__ Kbuf, const bf16* __restrict__ VTbuf,
    const f16* __restrict__ Bias, bf16* __restrict__ Hout)
{
    const int bh = blockIdx.x;                  // bh-major: XCD locality
    const int b = bh / NHEADS, h = bh % NHEADS;
    const int q0 = blockIdx.y * 128;
    const bf16* Kh  = Kbuf  + (size_t)bh * NSEQ * HD;   // [s][d]
    const bf16* VTh = VTbuf + (size_t)bh * NSEQ * HD;   // [d][s]

    __shared__ bf16 sK[64 * 64];
    __shared__ bf16 sVT[64 * 64];
    __shared__ bf16 sP[128 * 64];
    __shared__ float sL[128];

    const int t = threadIdx.x;
    const int w = t >> 6, l = t & 63, quad = l >> 4, l15 = l & 15;
    const int sw = l15 & 7;

    // staging geometry: 2 chunks (16B) per thread per buffer
    const int r0 = t >> 3, c0 = t & 7;
    const int r1 = r0 + 32;
    bf16* dK0 = &sK [r0*64 + ((c0 ^ (r0 & 7)) << 3)];
    bf16* dK1 = &sK [r1*64 + ((c0 ^ (r1 & 7)) << 3)];
    bf16* dV0 = &sVT[r0*64 + ((c0 ^ (r0 & 7)) << 3)];
    bf16* dV1 = &sVT[r1*64 + ((c0 ^ (r1 & 7)) << 3)];

    // fragment-linear bias base pointers (one per 16-row q group)
    const f16* bq0 = Bias + ((size_t)(blockIdx.y*8 + w*2 + 0) * NJT) * 1024 + quad*64 + l15*4;
    const f16* bq1 = Bias + ((size_t)(blockIdx.y*8 + w*2 + 1) * NJT) * 1024 + quad*64 + l15*4;

    // Q fragments (B-operand), 2 x 16 query rows per wave; queries = keys.
    bf16x8 qf[2][2];
    int qrow[2];
    #pragma unroll
    for (int qh = 0; qh < 2; ++qh) {
        qrow[qh] = q0 + w*32 + qh*16 + l15;
        int row = qrow[qh] > NSEQ - 1 ? NSEQ - 1 : qrow[qh];
        #pragma unroll
        for (int ks = 0; ks < 2; ++ks)
            qf[qh][ks] = *(const bf16x8*)&Kh[(size_t)row * HD + ks*32 + quad*8];
    }

    f32x4 Oacc[2][4] = {};
    float ps[2] = {0.f, 0.f};
    const int sPr0 = (w*32 + l15) * 64;

    uint4 kva, kvb, vva, vvb;
    f16x4 bpf[2][4];
#define PREFETCH(J, JT) do { \
        int ka_ = (J) + r0; if (ka_ > NSEQ-1) ka_ = NSEQ-1; \
        int kb_ = (J) + r1; if (kb_ > NSEQ-1) kb_ = NSEQ-1; \
        int ja_ = (J) + c0*8; if (ja_ > NSEQ-8) ja_ = NSEQ-8; \
        kva = *(const uint4*)&Kh [(size_t)ka_ * HD + c0*8]; \
        kvb = *(const uint4*)&Kh [(size_t)kb_ * HD + c0*8]; \
        vva = *(const uint4*)&VTh[(size_t)r0 * NSEQ + ja_]; \
        vvb = *(const uint4*)&VTh[(size_t)r1 * NSEQ + ja_]; \
        _Pragma("unroll") \
        for (int kt = 0; kt < 4; ++kt) { \
            bpf[0][kt] = *(const f16x4*)(bq0 + (size_t)(JT)*1024 + kt*256); \
            bpf[1][kt] = *(const f16x4*)(bq1 + (size_t)(JT)*1024 + kt*256); \
        } \
    } while (0)

    PREFETCH(0, 0);

    for (int jt = 0; jt < NJT; ++jt) {
        // stage current tile from prefetch regs (swizzled b128 writes)
        *(uint4*)dK0 = kva; *(uint4*)dK1 = kvb;
        *(uint4*)dV0 = vva; *(uint4*)dV1 = vvb;

        // consume current bias into sacc (frees bpf regs)
        f32x4 sacc[2][4];
        #pragma unroll
        for (int qh = 0; qh < 2; ++qh)
            #pragma unroll
            for (int kt = 0; kt < 4; ++kt)
                sacc[qh][kt] = (f32x4){(float)bpf[qh][kt].x, (float)bpf[qh][kt].y,
                                       (float)bpf[qh][kt].z, (float)bpf[qh][kt].w};

        // issue next tile's global loads (stay in flight across barriers)
        int jn  = (jt == NJT-1) ? 0 : (jt+1) * 64;
        int jtn = (jt == NJT-1) ? 0 : jt+1;
        PREFETCH(jn, jtn);

        bar();   // staged tile visible; prefetch still in flight

        // S^T += K_tile * Q^T
        #pragma unroll
        for (int ks = 0; ks < 2; ++ks) {
            bf16x8 af[4];
            #pragma unroll
            for (int kt = 0; kt < 4; ++kt) {
                int row = kt*16 + l15;
                af[kt] = *(const bf16x8*)&sK[row*64 + (((ks*4 + quad) ^ (row & 7)) << 3)];
            }
            __builtin_amdgcn_s_setprio(1);
            #pragma unroll
            for (int qh = 0; qh < 2; ++qh)
                #pragma unroll
                for (int kt = 0; kt < 4; ++kt)
                    sacc[qh][kt] = __builtin_amdgcn_mfma_f32_16x16x32_bf16(
                        af[kt], qf[qh][ks], sacc[qh][kt], 0, 0, 0);
            __builtin_amdgcn_s_setprio(0);
        }

        // P = exp2(S^T); swizzled b64 stores into wave-private sP rows
        #pragma unroll
        for (int qh = 0; qh < 2; ++qh)
            #pragma unroll
            for (int kt = 0; kt < 4; ++kt) {
                float p0 = __builtin_exp2f(sacc[qh][kt][0]);
                float p1 = __builtin_exp2f(sacc[qh][kt][1]);
                float p2 = __builtin_exp2f(sacc[qh][kt][2]);
                float p3 = __builtin_exp2f(sacc[qh][kt][3]);
                ps[qh] += (p0 + p1) + (p2 + p3);
                bf16x4 pv = { (bf16)p0, (bf16)p1, (bf16)p2, (bf16)p3 };
                int g = (kt*2 + (quad >> 1)) ^ sw;
                *(bf16x4*)&sP[sPr0 + qh*1024 + g*8 + (quad & 1)*4] = pv;
            }

        // O += P V
        #pragma unroll
        for (int ks = 0; ks < 2; ++ks) {
            bf16x8 bv[4];
            #pragma unroll
            for (int dt = 0; dt < 4; ++dt) {
                int row = dt*16 + l15;
                bv[dt] = *(const bf16x8*)&sVT[row*64 + (((ks*4 + quad) ^ (row & 7)) << 3)];
            }
            __builtin_amdgcn_s_setprio(1);
            #pragma unroll
            for (int qh = 0; qh < 2; ++qh) {
                bf16x8 ap = *(const bf16x8*)&sP[sPr0 + qh*1024 + (((ks*4 + quad) ^ sw) * 8)];
                #pragma unroll
                for (int dt = 0; dt < 4; ++dt)
                    Oacc[qh][dt] = __builtin_amdgcn_mfma_f32_16x16x32_bf16(
                        ap, bv[dt], Oacc[qh][dt], 0, 0, 0);
            }
            __builtin_amdgcn_s_setprio(0);
        }

        bar();   // all reads of sK/sVT done; next iter may overwrite
    }
#undef PREFETCH

    // row sums: reduce across quads, redistribute via wave-private sL rows
    #pragma unroll
    for (int qh = 0; qh < 2; ++qh) {
        float s = ps[qh];
        s += __shfl_xor(s, 16, 64);
        s += __shfl_xor(s, 32, 64);
        if (l < 16) sL[w*32 + qh*16 + l] = s;
    }

    #pragma unroll
    for (int qh = 0; qh < 2; ++qh)
        #pragma unroll
        for (int r = 0; r < 4; ++r) {
            int g = q0 + w*32 + qh*16 + quad*4 + r;
            if (g >= NSEQ) continue;
            float inv = 1.f / sL[w*32 + qh*16 + quad*4 + r];
            size_t base = ((size_t)(b * NSEQ) + g) * CDIM + h * HD;
            #pragma unroll
            for (int dt = 0; dt < 4; ++dt)
                Hout[base + dt*16 + l15] = (bf16)(Oacc[qh][dt][r] * inv);
        }
}

extern "C" void kernel_launch(void* const* d_in, const int* in_sizes, int n_in,
                              void* d_out, int out_size, void* d_ws, size_t ws_size,
                              hipStream_t stream) {
    const float* x      = (const float*)d_in[0];
    const float* qkv_w  = (const float*)d_in[1];
    const float* qkv_b  = (const float*)d_in[2];
    const float* proj_w = (const float*)d_in[3];
    const float* proj_b = (const float*)d_in[4];
    float* out = (float*)d_out;

    char* ws = (char*)d_ws;
    const size_t XBF_BYTES   = (size_t)MROWS * CDIM * 2;
    const size_t WKV_BYTES   = (size_t)2 * CDIM * CDIM * 2;
    const size_t PW_BYTES    = (size_t)CDIM * CDIM * 2;
    const size_t KBF_BYTES   = (size_t)BATCH * NHEADS * NSEQ * HD * 2;

    bf16* x_bf   = (bf16*)ws;
    bf16* wkv_bf = (bf16*)(ws + XBF_BYTES);
    bf16* pw_bf  = (bf16*)(ws + XBF_BYTES + WKV_BYTES);
    bf16* k_bf   = (bf16*)(ws + XBF_BYTES + WKV_BYTES + PW_BYTES);
    bf16* vt_bf  = (bf16*)(ws + XBF_BYTES + WKV_BYTES + PW_BYTES + KBF_BYTES);
    f16*  bias_t = (f16*)(ws + XBF_BYTES + WKV_BYTES + PW_BYTES + KBF_BYTES + KBF_BYTES);

    // fused prep: fragment-linear f16 bias table + all casts
    {
        int total = NQ16 * NJT * 1024 + MROWS * CDIM / 4
                  + 2 * CDIM * CDIM / 4 + CDIM * CDIM / 4;
        prep_kernel<<<dim3((total + 255) / 256), dim3(256), 0, stream>>>(
            x, qkv_w + (size_t)CDIM * CDIM, proj_w, x_bf, wkv_bf, pw_bf, bias_t);
    }

    // qkv GEMM (k & v only): M=8256, N=1536, K=768 ; writes K' and V^T
    {
        dim3 grid(1536 / 128, (MROWS + 127) / 128);
        gemm_nt<1><<<grid, dim3(256), 0, stream>>>(x_bf, wkv_bf, qkv_b + CDIM,
                                                   nullptr, k_bf, vt_bf,
                                                   MROWS, 1536, CDIM);
    }

    // attention -> hidden (reuse x_bf buffer); grid (bh, qtile)
    {
        dim3 grid(BATCH * NHEADS, (NSEQ + 127) / 128);
        attn_kernel<<<grid, dim3(256), 0, stream>>>(k_bf, vt_bf, bias_t, x_bf);
    }

    // proj GEMM: out = hidden @ proj_w^T + proj_b, fp32 out
    {
        dim3 grid(CDIM / 128, (MROWS + 127) / 128);
        gemm_nt<0><<<grid, dim3(256), 0, stream>>>(x_bf, pw_bf, proj_b,
                                                   out, nullptr, nullptr,
                                                   MROWS, CDIM, CDIM);
    }
}

// Round 5
// 227.500 us; speedup vs baseline: 1.7026x; 1.0477x over previous
//
#include <hip/hip_runtime.h>
#include <stdint.h>

typedef __bf16 bf16;
typedef _Float16 f16;
typedef __bf16 bf16x8 __attribute__((ext_vector_type(8)));
typedef __bf16 bf16x4 __attribute__((ext_vector_type(4)));
typedef float f32x4 __attribute__((ext_vector_type(4)));

#define NSEQ 1032
#define BATCH 8
#define NHEADS 12
#define HD 64
#define CDIM 768
#define MROWS (BATCH * NSEQ)   // 8256
#define PREFIX 8
#define NJT 17                 // j-tiles of 64 keys (covers 1088)
#define NQ16 72                // 16-row q groups (covers 1152)
#define KSTRIDE 1152           // padded K rows per head (zeros beyond 1031)
#define VSTRIDE 1152           // padded V^T cols per head (zeros beyond 1031)
// sqrt(0.125 * log2(e)) : folds hd^-0.5 and exp->exp2 into K (both sides of K.K^T).
#define KSCALE 0.42466090f

__device__ __forceinline__ unsigned short f2bf_rne(float f) {
    union { float f; uint32_t u; } v; v.f = f;
    uint32_t u = v.u;
    return (unsigned short)((u + 0x7fffu + ((u >> 16) & 1u)) >> 16);
}

__device__ __forceinline__ void gload_lds16(const bf16* g, bf16* l) {
    __builtin_amdgcn_global_load_lds(
        (const __attribute__((address_space(1))) void*)g,
        (__attribute__((address_space(3))) void*)l, 16, 0, 0);
}

__device__ __forceinline__ void cast4(const float* src, bf16* dst, int i) {
    float4 f = ((const float4*)src)[i];
    ushort4 o;
    o.x = f2bf_rne(f.x); o.y = f2bf_rne(f.y);
    o.z = f2bf_rne(f.z); o.w = f2bf_rne(f.w);
    ((ushort4*)dst)[i] = o;
}

// Raw barrier: drains LDS ops only; global prefetch loads stay in flight.
__device__ __forceinline__ void bar() {
    asm volatile("s_waitcnt lgkmcnt(0)" ::: "memory");
    __builtin_amdgcn_s_barrier();
    asm volatile("" ::: "memory");
}

// Fused prep: f32 fragment-linear bias table + casts + K/V^T pad zeroing.
// Bias layout: [q16][jt][kt][quad][l15][r] f32, value = log2e * gauss(q,k),
// q = q16*16+l15, k = jt*64+kt*16+quad*4+r -> one coalesced b128/lane/fragment.
__global__ void prep_kernel(const float* __restrict__ x,
                            const float* __restrict__ wkv,
                            const float* __restrict__ pw,
                            bf16* __restrict__ x_bf, bf16* __restrict__ wkv_bf,
                            bf16* __restrict__ pw_bf, float* __restrict__ Bias,
                            bf16* __restrict__ k_bf, bf16* __restrict__ vt_bf) {
    const int N0 = NQ16 * NJT * 1024;          // bias elems
    const int N1 = MROWS * CDIM / 4;
    const int N2 = 2 * CDIM * CDIM / 4;
    const int N3 = CDIM * CDIM / 4;
    const int N4 = BATCH * NHEADS * 120 * 8;   // K pad rows 1032..1151, 8 chunks
    const int N5 = BATCH * NHEADS * 64 * 15;   // V^T pad cols 1032..1151
    int i = blockIdx.x * blockDim.x + threadIdx.x;
    if (i < N0) {
        int r    = i & 3;
        int l15  = (i >> 2) & 15;
        int quad = (i >> 6) & 3;
        int kt   = (i >> 8) & 3;
        int rest = i >> 10;                    // q16*NJT + jt
        int q16  = rest / NJT;
        int jt   = rest - q16 * NJT;
        int q = q16 * 16 + l15;
        int k = jt * 64 + kt * 16 + quad * 4 + r;
        float v;
        if (k >= NSEQ) v = -65504.f;           // exp2 -> 0
        else if (q < PREFIX || q >= NSEQ || k < PREFIX) v = 0.f;
        else {
            int rp = q - PREFIX, cp = k - PREFIX;
            int d1 = (rp >> 5) - (cp >> 5);
            int d2 = (rp & 31) - (cp & 31);
            v = 1.44269504f * __expf(-0.02f * (float)(d1 * d1 + d2 * d2));
        }
        Bias[i] = v;
        return;
    }
    i -= N0;
    if (i < N1) { cast4(x, x_bf, i); return; }
    i -= N1;
    if (i < N2) { cast4(wkv, wkv_bf, i); return; }
    i -= N2;
    if (i < N3) { cast4(pw, pw_bf, i); return; }
    i -= N3;
    if (i < N4) {
        int bh = i / 960, rem = i - bh * 960;
        int row = 1032 + (rem >> 3), ch = rem & 7;
        uint4 z = {0u, 0u, 0u, 0u};
        *(uint4*)&k_bf[((size_t)bh * KSTRIDE + row) * HD + ch * 8] = z;
        return;
    }
    i -= N4;
    if (i < N5) {
        int bh = i / 960, rem = i - bh * 960;
        int d = rem / 15, ch = rem - d * 15;
        uint4 z = {0u, 0u, 0u, 0u};
        *(uint4*)&vt_bf[((size_t)bh * HD + d) * VSTRIDE + 1032 + ch * 8] = z;
    }
}

// NT GEMM, m97-style DMA staging.
// EPI=0: fp32 out. EPI=1: n<768 -> K' (scaled KSCALE) [B,H,s(1152),d];
//                         n>=768 -> V^T layout [B,H,d,s(1152)], bf16x4 stores.
template<int EPI>
__global__ __launch_bounds__(256) void gemm_nt(
    const bf16* __restrict__ A, const bf16* __restrict__ B,
    const float* __restrict__ bias,
    float* __restrict__ Cout, bf16* __restrict__ Kout, bf16* __restrict__ Vout,
    int M, int N, int K)
{
    __shared__ bf16 sA[128 * 32];
    __shared__ bf16 sB[128 * 32];
    const int t = threadIdx.x;
    const int w = t >> 6;
    const int l = t & 63;
    const int quad = l >> 4;
    const int l15 = l & 15;
    const int wy = w >> 1, wx = w & 1;
    const int m0 = blockIdx.y * 128;
    const int n0 = blockIdx.x * 128;
    const int co = (quad ^ ((l15 >> 1) & 3)) * 8;

    int r0 = t >> 2,          c0 = (t & 3) ^ ((r0 >> 1) & 3);
    int r1 = (t + 256) >> 2,  c1 = ((t + 256) & 3) ^ ((r1 >> 1) & 3);
    int ra0 = m0 + r0; if (ra0 >= M) ra0 = M - 1;
    int ra1 = m0 + r1; if (ra1 >= M) ra1 = M - 1;
    const bf16* gA0 = A + (size_t)ra0 * K + c0 * 8;
    const bf16* gA1 = A + (size_t)ra1 * K + c1 * 8;
    const bf16* gB0 = B + (size_t)(n0 + r0) * K + c0 * 8;
    const bf16* gB1 = B + (size_t)(n0 + r1) * K + c1 * 8;
    bf16* dA0 = &sA[(size_t)(w * 64) * 8];
    bf16* dA1 = &sA[(size_t)(256 + w * 64) * 8];
    bf16* dB0 = &sB[(size_t)(w * 64) * 8];
    bf16* dB1 = &sB[(size_t)(256 + w * 64) * 8];

    f32x4 acc[4][4] = {};

    for (int k0 = 0; k0 < K; k0 += 32) {
        __syncthreads();
        gload_lds16(gA0, dA0); gload_lds16(gA1, dA1);
        gload_lds16(gB0, dB0); gload_lds16(gB1, dB1);
        gA0 += 32; gA1 += 32; gB0 += 32; gB1 += 32;
        __syncthreads();
        bf16x8 af[4], bq[4];
        #pragma unroll
        for (int mt = 0; mt < 4; ++mt)
            af[mt] = *(const bf16x8*)&sA[(wy*64 + mt*16 + l15) * 32 + co];
        #pragma unroll
        for (int nt = 0; nt < 4; ++nt)
            bq[nt] = *(const bf16x8*)&sB[(wx*64 + nt*16 + l15) * 32 + co];
        #pragma unroll
        for (int mt = 0; mt < 4; ++mt)
            #pragma unroll
            for (int nt = 0; nt < 4; ++nt)
                acc[mt][nt] = __builtin_amdgcn_mfma_f32_16x16x32_bf16(af[mt], bq[nt], acc[mt][nt], 0, 0, 0);
    }

    if (EPI == 0) {
        #pragma unroll
        for (int mt = 0; mt < 4; ++mt) {
            #pragma unroll
            for (int r = 0; r < 4; ++r) {
                int m = m0 + wy*64 + mt*16 + quad*4 + r;
                if (m >= M) continue;
                #pragma unroll
                for (int nt = 0; nt < 4; ++nt) {
                    int n = n0 + wx*64 + nt*16 + l15;
                    Cout[(size_t)m * N + n] = acc[mt][nt][r] + bias[n];
                }
            }
        }
    } else {
        #pragma unroll
        for (int mt = 0; mt < 4; ++mt) {
            int mb = m0 + wy*64 + mt*16 + quad*4;     // 4-aligned; stays in one (b,s) run
            if (mb >= M) continue;
            int b = mb / NSEQ, s = mb % NSEQ;
            #pragma unroll
            for (int nt = 0; nt < 4; ++nt) {
                int n = n0 + wx*64 + nt*16 + l15;
                float bn = bias[n];
                if (n < CDIM) {
                    int h = n >> 6, d = n & 63;
                    bf16* kp = &Kout[(((size_t)(b*NHEADS + h))*KSTRIDE + s)*HD + d];
                    #pragma unroll
                    for (int r = 0; r < 4; ++r)
                        kp[(size_t)r * HD] = (bf16)((acc[mt][nt][r] + bn) * KSCALE);
                } else {
                    int n2 = n - CDIM;
                    int h = n2 >> 6, d = n2 & 63;
                    bf16x4 pv = { (bf16)(acc[mt][nt][0] + bn), (bf16)(acc[mt][nt][1] + bn),
                                  (bf16)(acc[mt][nt][2] + bn), (bf16)(acc[mt][nt][3] + bn) };
                    *(bf16x4*)&Vout[(((size_t)(b*NHEADS + h))*HD + d)*VSTRIDE + s] = pv;
                }
            }
        }
    }
}

// Attention: 4 waves x 32 q-rows, double-buffered swizzled LDS staging
// (one barrier/iter), clamp-free pointer-bump prefetch (padded K/V^T),
// f32 fragment-linear bias direct into MFMA C, row sums via ones-MFMA.
__global__ __launch_bounds__(256) void attn_kernel(
    const bf16* __restrict__ Kbuf, const bf16* __restrict__ VTbuf,
    const float* __restrict__ Bias, bf16* __restrict__ Hout)
{
    const int bh = blockIdx.x;                  // bh-major: XCD locality
    const int b = bh / NHEADS, h = bh % NHEADS;
    const int q0 = blockIdx.y * 128;
    const bf16* Kh  = Kbuf  + (size_t)bh * KSTRIDE * HD;   // [s][d]
    const bf16* VTh = VTbuf + (size_t)bh * HD * VSTRIDE;   // [d][s]

    __shared__ bf16 sK[2][64 * 64];
    __shared__ bf16 sVT[2][64 * 64];
    __shared__ bf16 sP[128 * 64];

    const int t = threadIdx.x;
    const int w = t >> 6, l = t & 63, quad = l >> 4, l15 = l & 15;
    const int sw = l15 & 7;

    // staging geometry: 2 swizzled b128 chunks per thread per buffer
    const int r0 = t >> 3, c0 = t & 7;
    const int r1 = r0 + 32;
    const int dk0 = r0*64 + ((c0 ^ (r0 & 7)) << 3);
    const int dk1 = r1*64 + ((c0 ^ (r1 & 7)) << 3);

    // clamp-free global pointers (pure bumps; pads make every tile safe)
    const bf16* pK0 = Kh + (size_t)r0 * HD + c0 * 8;
    const bf16* pK1 = Kh + (size_t)r1 * HD + c0 * 8;
    const bf16* pV0 = VTh + (size_t)r0 * VSTRIDE + c0 * 8;
    const bf16* pV1 = VTh + (size_t)r1 * VSTRIDE + c0 * 8;
    const float* pB0 = Bias + ((size_t)(blockIdx.y*8 + w*2 + 0) * NJT) * 1024 + quad*64 + l15*4;
    const float* pB1 = Bias + ((size_t)(blockIdx.y*8 + w*2 + 1) * NJT) * 1024 + quad*64 + l15*4;

    // Q fragments (B-operand), 2 x 16 query rows per wave; queries = keys.
    bf16x8 qf[2][2];
    #pragma unroll
    for (int qh = 0; qh < 2; ++qh) {
        int row = q0 + w*32 + qh*16 + l15;      // < 1152, pad rows are zero
        #pragma unroll
        for (int ks = 0; ks < 2; ++ks)
            qf[qh][ks] = *(const bf16x8*)&Kh[(size_t)row * HD + ks*32 + quad*8];
    }

    bf16x8 onesb;
    #pragma unroll
    for (int e = 0; e < 8; ++e) onesb[e] = (bf16)1.0f;

    f32x4 Oacc[2][4] = {};
    f32x4 Lacc[2] = {};
    const int sPr0 = (w*32 + l15) * 64;

    uint4 kva, kvb, vva, vvb;
    f32x4 bpf[2][4];

#define PREFETCH() do { \
        kva = *(const uint4*)pK0; kvb = *(const uint4*)pK1; \
        vva = *(const uint4*)pV0; vvb = *(const uint4*)pV1; \
        pK0 += 64*HD; pK1 += 64*HD; pV0 += 64; pV1 += 64; \
        _Pragma("unroll") \
        for (int kt = 0; kt < 4; ++kt) { \
            bpf[0][kt] = *(const f32x4*)(pB0 + kt*256); \
            bpf[1][kt] = *(const f32x4*)(pB1 + kt*256); \
        } \
        pB0 += 1024; pB1 += 1024; \
    } while (0)

#define ITER(CUR) do { \
        *(uint4*)&sK[CUR][dk0] = kva; *(uint4*)&sK[CUR][dk1] = kvb; \
        *(uint4*)&sVT[CUR][dk0] = vva; *(uint4*)&sVT[CUR][dk1] = vvb; \
        f32x4 sacc[2][4]; \
        _Pragma("unroll") \
        for (int qh = 0; qh < 2; ++qh) \
            _Pragma("unroll") \
            for (int kt = 0; kt < 4; ++kt) \
                sacc[qh][kt] = bpf[qh][kt]; \
        PREFETCH(); \
        bar(); \
        _Pragma("unroll") \
        for (int ks = 0; ks < 2; ++ks) { \
            bf16x8 af[4]; \
            _Pragma("unroll") \
            for (int kt = 0; kt < 4; ++kt) \
                af[kt] = *(const bf16x8*)&sK[CUR][(kt*16 + l15)*64 + (((ks*4 + quad) ^ sw) << 3)]; \
            __builtin_amdgcn_s_setprio(1); \
            _Pragma("unroll") \
            for (int qh = 0; qh < 2; ++qh) \
                _Pragma("unroll") \
                for (int kt = 0; kt < 4; ++kt) \
                    sacc[qh][kt] = __builtin_amdgcn_mfma_f32_16x16x32_bf16( \
                        af[kt], qf[qh][ks], sacc[qh][kt], 0, 0, 0); \
            __builtin_amdgcn_s_setprio(0); \
        } \
        _Pragma("unroll") \
        for (int qh = 0; qh < 2; ++qh) \
            _Pragma("unroll") \
            for (int kt = 0; kt < 4; ++kt) { \
                float p0 = __builtin_exp2f(sacc[qh][kt][0]); \
                float p1 = __builtin_exp2f(sacc[qh][kt][1]); \
                float p2 = __builtin_exp2f(sacc[qh][kt][2]); \
                float p3 = __builtin_exp2f(sacc[qh][kt][3]); \
                bf16x4 pv = { (bf16)p0, (bf16)p1, (bf16)p2, (bf16)p3 }; \
                int g = (kt*2 + (quad >> 1)) ^ sw; \
                *(bf16x4*)&sP[sPr0 + qh*1024 + g*8 + (quad & 1)*4] = pv; \
            } \
        _Pragma("unroll") \
        for (int ks = 0; ks < 2; ++ks) { \
            bf16x8 bv[4]; \
            _Pragma("unroll") \
            for (int dt = 0; dt < 4; ++dt) \
                bv[dt] = *(const bf16x8*)&sVT[CUR][(dt*16 + l15)*64 + (((ks*4 + quad) ^ sw) << 3)]; \
            __builtin_amdgcn_s_setprio(1); \
            _Pragma("unroll") \
            for (int qh = 0; qh < 2; ++qh) { \
                bf16x8 ap = *(const bf16x8*)&sP[sPr0 + qh*1024 + (((ks*4 + quad) ^ sw) * 8)]; \
                _Pragma("unroll") \
                for (int dt = 0; dt < 4; ++dt) \
                    Oacc[qh][dt] = __builtin_amdgcn_mfma_f32_16x16x32_bf16( \
                        ap, bv[dt], Oacc[qh][dt], 0, 0, 0); \
                Lacc[qh] = __builtin_amdgcn_mfma_f32_16x16x32_bf16( \
                    ap, onesb, Lacc[qh], 0, 0, 0); \
            } \
            __builtin_amdgcn_s_setprio(0); \
        } \
    } while (0)

    PREFETCH();      // tile 0
    ITER(0);         // jt 0
    #pragma unroll 1
    for (int it = 0; it < (NJT - 1) / 2; ++it) {   // jt 1..16 as 8 pairs
        ITER(1);
        ITER(0);
    }
#undef ITER
#undef PREFETCH

    // epilogue: Lacc holds per-row sums (rows quad*4+r) lane-locally
    #pragma unroll
    for (int qh = 0; qh < 2; ++qh)
        #pragma unroll
        for (int r = 0; r < 4; ++r) {
            int g = q0 + w*32 + qh*16 + quad*4 + r;
            if (g >= NSEQ) continue;
            float inv = 1.f / Lacc[qh][r];
            size_t base = ((size_t)(b * NSEQ) + g) * CDIM + h * HD;
            #pragma unroll
            for (int dt = 0; dt < 4; ++dt)
                Hout[base + dt*16 + l15] = (bf16)(Oacc[qh][dt][r] * inv);
        }
}

extern "C" void kernel_launch(void* const* d_in, const int* in_sizes, int n_in,
                              void* d_out, int out_size, void* d_ws, size_t ws_size,
                              hipStream_t stream) {
    const float* x      = (const float*)d_in[0];
    const float* qkv_w  = (const float*)d_in[1];
    const float* qkv_b  = (const float*)d_in[2];
    const float* proj_w = (const float*)d_in[3];
    const float* proj_b = (const float*)d_in[4];
    float* out = (float*)d_out;

    char* ws = (char*)d_ws;
    const size_t XBF_BYTES   = (size_t)MROWS * CDIM * 2;                    // 12.68 MB
    const size_t WKV_BYTES   = (size_t)2 * CDIM * CDIM * 2;                 //  2.36 MB
    const size_t PW_BYTES    = (size_t)CDIM * CDIM * 2;                     //  1.18 MB
    const size_t BIAS_BYTES  = (size_t)NQ16 * NJT * 1024 * 4;               //  5.01 MB
    const size_t KBF_BYTES   = (size_t)BATCH * NHEADS * KSTRIDE * HD * 2;   // 14.16 MB

    bf16*  x_bf   = (bf16*)ws;
    bf16*  wkv_bf = (bf16*)(ws + XBF_BYTES);
    bf16*  pw_bf  = (bf16*)(ws + XBF_BYTES + WKV_BYTES);
    float* bias_t = (float*)(ws + XBF_BYTES + WKV_BYTES + PW_BYTES);
    bf16*  k_bf   = (bf16*)(ws + XBF_BYTES + WKV_BYTES + PW_BYTES + BIAS_BYTES);
    bf16*  vt_bf  = (bf16*)(ws + XBF_BYTES + WKV_BYTES + PW_BYTES + BIAS_BYTES + KBF_BYTES);
    // bias placed before k_bf so the harmless tile-17 bias over-read lands in k_bf

    // fused prep: f32 fragment-linear bias + all casts + K/V^T pad zeroing
    {
        int total = NQ16 * NJT * 1024 + MROWS * CDIM / 4
                  + 2 * CDIM * CDIM / 4 + CDIM * CDIM / 4
                  + BATCH * NHEADS * 120 * 8 + BATCH * NHEADS * 64 * 15;
        prep_kernel<<<dim3((total + 255) / 256), dim3(256), 0, stream>>>(
            x, qkv_w + (size_t)CDIM * CDIM, proj_w, x_bf, wkv_bf, pw_bf, bias_t,
            k_bf, vt_bf);
    }

    // qkv GEMM (k & v only): M=8256, N=1536, K=768 ; writes K' and V^T (padded)
    {
        dim3 grid(1536 / 128, (MROWS + 127) / 128);
        gemm_nt<1><<<grid, dim3(256), 0, stream>>>(x_bf, wkv_bf, qkv_b + CDIM,
                                                   nullptr, k_bf, vt_bf,
                                                   MROWS, 1536, CDIM);
    }

    // attention -> hidden (reuse x_bf buffer); grid (bh, qtile)
    {
        dim3 grid(BATCH * NHEADS, (NSEQ + 127) / 128);
        attn_kernel<<<grid, dim3(256), 0, stream>>>(k_bf, vt_bf, bias_t, x_bf);
    }

    // proj GEMM: out = hidden @ proj_w^T + proj_b, fp32 out
    {
        dim3 grid(CDIM / 128, (MROWS + 127) / 128);
        gemm_nt<0><<<grid, dim3(256), 0, stream>>>(x_bf, pw_bf, proj_b,
                                                   out, nullptr, nullptr,
                                                   MROWS, CDIM, CDIM);
    }
}

// Round 6
// 225.624 us; speedup vs baseline: 1.7167x; 1.0083x over previous
//
#include <hip/hip_runtime.h>
#include <stdint.h>

typedef __bf16 bf16;
typedef _Float16 f16;
typedef __bf16 bf16x8 __attribute__((ext_vector_type(8)));
typedef __bf16 bf16x4 __attribute__((ext_vector_type(4)));
typedef float f32x4 __attribute__((ext_vector_type(4)));

#define NSEQ 1032
#define BATCH 8
#define NHEADS 12
#define HD 64
#define CDIM 768
#define MROWS (BATCH * NSEQ)   // 8256
#define PREFIX 8
#define NJT 17                 // j-tiles of 64 keys (covers 1088)
#define NQ16 72                // 16-row q groups (covers 1152)
#define KSTRIDE 1152           // padded K rows per head (zeros beyond 1031)
#define VSTRIDE 1152           // padded V^T cols per head (zeros beyond 1031)
// sqrt(0.125 * log2(e)) : folds hd^-0.5 and exp->exp2 into K (both sides of K.K^T).
#define KSCALE 0.42466090f

__device__ __forceinline__ unsigned short f2bf_rne(float f) {
    union { float f; uint32_t u; } v; v.f = f;
    uint32_t u = v.u;
    return (unsigned short)((u + 0x7fffu + ((u >> 16) & 1u)) >> 16);
}

__device__ __forceinline__ void gload_lds16(const bf16* g, bf16* l) {
    __builtin_amdgcn_global_load_lds(
        (const __attribute__((address_space(1))) void*)g,
        (__attribute__((address_space(3))) void*)l, 16, 0, 0);
}

__device__ __forceinline__ void cast4(const float* src, bf16* dst, int i) {
    float4 f = ((const float4*)src)[i];
    ushort4 o;
    o.x = f2bf_rne(f.x); o.y = f2bf_rne(f.y);
    o.z = f2bf_rne(f.z); o.w = f2bf_rne(f.w);
    ((ushort4*)dst)[i] = o;
}

// Raw barrier: drains LDS ops only; global prefetch loads stay in flight.
__device__ __forceinline__ void bar() {
    asm volatile("s_waitcnt lgkmcnt(0)" ::: "memory");
    __builtin_amdgcn_s_barrier();
    asm volatile("" ::: "memory");
}

// GEMM barrier: drains the async global->LDS stage only (no ds_writes exist).
__device__ __forceinline__ void gbar() {
    asm volatile("s_waitcnt vmcnt(0)" ::: "memory");
    __builtin_amdgcn_s_barrier();
    asm volatile("" ::: "memory");
}

// Fused prep: f32 fragment-linear bias table + casts + K/V^T pad zeroing.
// Bias layout: [q16][jt][kt][quad][l15][r] f32, value = log2e * gauss(q,k),
// q = q16*16+l15, k = jt*64+kt*16+quad*4+r -> one coalesced b128/lane/fragment.
__global__ void prep_kernel(const float* __restrict__ x,
                            const float* __restrict__ wkv,
                            const float* __restrict__ pw,
                            bf16* __restrict__ x_bf, bf16* __restrict__ wkv_bf,
                            bf16* __restrict__ pw_bf, float* __restrict__ Bias,
                            bf16* __restrict__ k_bf, bf16* __restrict__ vt_bf) {
    const int N0 = NQ16 * NJT * 1024;          // bias elems
    const int N1 = MROWS * CDIM / 4;
    const int N2 = 2 * CDIM * CDIM / 4;
    const int N3 = CDIM * CDIM / 4;
    const int N4 = BATCH * NHEADS * 120 * 8;   // K pad rows 1032..1151, 8 chunks
    const int N5 = BATCH * NHEADS * 64 * 15;   // V^T pad cols 1032..1151
    int i = blockIdx.x * blockDim.x + threadIdx.x;
    if (i < N0) {
        int r    = i & 3;
        int l15  = (i >> 2) & 15;
        int quad = (i >> 6) & 3;
        int kt   = (i >> 8) & 3;
        int rest = i >> 10;                    // q16*NJT + jt
        int q16  = rest / NJT;
        int jt   = rest - q16 * NJT;
        int q = q16 * 16 + l15;
        int k = jt * 64 + kt * 16 + quad * 4 + r;
        float v;
        if (k >= NSEQ) v = -65504.f;           // exp2 -> 0
        else if (q < PREFIX || q >= NSEQ || k < PREFIX) v = 0.f;
        else {
            int rp = q - PREFIX, cp = k - PREFIX;
            int d1 = (rp >> 5) - (cp >> 5);
            int d2 = (rp & 31) - (cp & 31);
            v = 1.44269504f * __expf(-0.02f * (float)(d1 * d1 + d2 * d2));
        }
        Bias[i] = v;
        return;
    }
    i -= N0;
    if (i < N1) { cast4(x, x_bf, i); return; }
    i -= N1;
    if (i < N2) { cast4(wkv, wkv_bf, i); return; }
    i -= N2;
    if (i < N3) { cast4(pw, pw_bf, i); return; }
    i -= N3;
    if (i < N4) {
        int bh = i / 960, rem = i - bh * 960;
        int row = 1032 + (rem >> 3), ch = rem & 7;
        uint4 z = {0u, 0u, 0u, 0u};
        *(uint4*)&k_bf[((size_t)bh * KSTRIDE + row) * HD + ch * 8] = z;
        return;
    }
    i -= N4;
    if (i < N5) {
        int bh = i / 960, rem = i - bh * 960;
        int d = rem / 15, ch = rem - d * 15;
        uint4 z = {0u, 0u, 0u, 0u};
        *(uint4*)&vt_bf[((size_t)bh * HD + d) * VSTRIDE + 1032 + ch * 8] = z;
    }
}

// NT GEMM, 2-phase pipelined DMA staging: double-buffered LDS, next tile's
// global_load_lds issued BEFORE computing the current tile, one
// vmcnt(0)+barrier per K-step (old structure drained latency every step).
// EPI=0: fp32 out. EPI=1: n<768 -> K' (scaled KSCALE) [B,H,s(1152),d];
//                         n>=768 -> V^T layout [B,H,d,s(1152)], bf16x4 stores.
template<int EPI>
__global__ __launch_bounds__(256) void gemm_nt(
    const bf16* __restrict__ A, const bf16* __restrict__ B,
    const float* __restrict__ bias,
    float* __restrict__ Cout, bf16* __restrict__ Kout, bf16* __restrict__ Vout,
    int M, int N, int K)
{
    __shared__ bf16 sA[2][128 * 32];
    __shared__ bf16 sB[2][128 * 32];
    const int t = threadIdx.x;
    const int w = t >> 6;
    const int l = t & 63;
    const int quad = l >> 4;
    const int l15 = l & 15;
    const int wy = w >> 1, wx = w & 1;
    const int m0 = blockIdx.y * 128;
    const int n0 = blockIdx.x * 128;
    const int co = (quad ^ ((l15 >> 1) & 3)) * 8;

    int r0 = t >> 2,          c0 = (t & 3) ^ ((r0 >> 1) & 3);
    int r1 = (t + 256) >> 2,  c1 = ((t + 256) & 3) ^ ((r1 >> 1) & 3);
    int ra0 = m0 + r0; if (ra0 >= M) ra0 = M - 1;
    int ra1 = m0 + r1; if (ra1 >= M) ra1 = M - 1;
    const bf16* gA0 = A + (size_t)ra0 * K + c0 * 8;
    const bf16* gA1 = A + (size_t)ra1 * K + c1 * 8;
    const bf16* gB0 = B + (size_t)(n0 + r0) * K + c0 * 8;
    const bf16* gB1 = B + (size_t)(n0 + r1) * K + c1 * 8;
    const int oA0 = (w * 64) * 8;
    const int oA1 = (256 + w * 64) * 8;

    f32x4 acc[4][4] = {};

#define STAGE(BUF) do { \
        gload_lds16(gA0, &sA[BUF][oA0]); gload_lds16(gA1, &sA[BUF][oA1]); \
        gload_lds16(gB0, &sB[BUF][oA0]); gload_lds16(gB1, &sB[BUF][oA1]); \
        gA0 += 32; gA1 += 32; gB0 += 32; gB1 += 32; \
    } while (0)

#define COMPUTE(BUF) do { \
        bf16x8 af_[4], bq_[4]; \
        _Pragma("unroll") \
        for (int mt = 0; mt < 4; ++mt) \
            af_[mt] = *(const bf16x8*)&sA[BUF][(wy*64 + mt*16 + l15) * 32 + co]; \
        _Pragma("unroll") \
        for (int nt = 0; nt < 4; ++nt) \
            bq_[nt] = *(const bf16x8*)&sB[BUF][(wx*64 + nt*16 + l15) * 32 + co]; \
        _Pragma("unroll") \
        for (int mt = 0; mt < 4; ++mt) \
            _Pragma("unroll") \
            for (int nt = 0; nt < 4; ++nt) \
                acc[mt][nt] = __builtin_amdgcn_mfma_f32_16x16x32_bf16( \
                    af_[mt], bq_[nt], acc[mt][nt], 0, 0, 0); \
    } while (0)

    STAGE(0);
    gbar();
    const int NP = K / 64;                 // K%64==0 for both call sites
    #pragma unroll 1
    for (int p = 0; p < NP; ++p) {
        STAGE(1);          // tile 2p+1 in flight while computing tile 2p
        COMPUTE(0);
        gbar();
        if (p + 1 < NP) STAGE(0);          // tile 2p+2
        COMPUTE(1);
        gbar();
    }
#undef STAGE
#undef COMPUTE

    if (EPI == 0) {
        #pragma unroll
        for (int mt = 0; mt < 4; ++mt) {
            #pragma unroll
            for (int r = 0; r < 4; ++r) {
                int m = m0 + wy*64 + mt*16 + quad*4 + r;
                if (m >= M) continue;
                #pragma unroll
                for (int nt = 0; nt < 4; ++nt) {
                    int n = n0 + wx*64 + nt*16 + l15;
                    Cout[(size_t)m * N + n] = acc[mt][nt][r] + bias[n];
                }
            }
        }
    } else {
        #pragma unroll
        for (int mt = 0; mt < 4; ++mt) {
            int mb = m0 + wy*64 + mt*16 + quad*4;     // 4-aligned; stays in one (b,s) run
            if (mb >= M) continue;
            int b = mb / NSEQ, s = mb % NSEQ;
            #pragma unroll
            for (int nt = 0; nt < 4; ++nt) {
                int n = n0 + wx*64 + nt*16 + l15;
                float bn = bias[n];
                if (n < CDIM) {
                    int h = n >> 6, d = n & 63;
                    bf16* kp = &Kout[(((size_t)(b*NHEADS + h))*KSTRIDE + s)*HD + d];
                    #pragma unroll
                    for (int r = 0; r < 4; ++r)
                        kp[(size_t)r * HD] = (bf16)((acc[mt][nt][r] + bn) * KSCALE);
                } else {
                    int n2 = n - CDIM;
                    int h = n2 >> 6, d = n2 & 63;
                    bf16x4 pv = { (bf16)(acc[mt][nt][0] + bn), (bf16)(acc[mt][nt][1] + bn),
                                  (bf16)(acc[mt][nt][2] + bn), (bf16)(acc[mt][nt][3] + bn) };
                    *(bf16x4*)&Vout[(((size_t)(b*NHEADS + h))*HD + d)*VSTRIDE + s] = pv;
                }
            }
        }
    }
}

// Attention: 4 waves x 32 q-rows, double-buffered swizzled LDS staging,
// clamp-free pointer-bump prefetch (padded K/V^T), bias prefetched into
// named register BANKS that the QK^T MFMA accumulates into directly
// (no sacc copy), row sums via ones-MFMA.
__global__ __launch_bounds__(256) void attn_kernel(
    const bf16* __restrict__ Kbuf, const bf16* __restrict__ VTbuf,
    const float* __restrict__ Bias, bf16* __restrict__ Hout)
{
    const int bh = blockIdx.x;                  // bh-major: XCD locality
    const int b = bh / NHEADS, h = bh % NHEADS;
    const int q0 = blockIdx.y * 128;
    const bf16* Kh  = Kbuf  + (size_t)bh * KSTRIDE * HD;   // [s][d]
    const bf16* VTh = VTbuf + (size_t)bh * HD * VSTRIDE;   // [d][s]

    __shared__ bf16 sK[2][64 * 64];
    __shared__ bf16 sVT[2][64 * 64];
    __shared__ bf16 sP[128 * 64];

    const int t = threadIdx.x;
    const int w = t >> 6, l = t & 63, quad = l >> 4, l15 = l & 15;
    const int sw = l15 & 7;

    // staging geometry: 2 swizzled b128 chunks per thread per buffer
    const int r0 = t >> 3, c0 = t & 7;
    const int r1 = r0 + 32;
    const int dk0 = r0*64 + ((c0 ^ (r0 & 7)) << 3);
    const int dk1 = r1*64 + ((c0 ^ (r1 & 7)) << 3);

    // clamp-free global pointers (pure bumps; pads make every tile safe)
    const bf16* pK0 = Kh + (size_t)r0 * HD + c0 * 8;
    const bf16* pK1 = Kh + (size_t)r1 * HD + c0 * 8;
    const bf16* pV0 = VTh + (size_t)r0 * VSTRIDE + c0 * 8;
    const bf16* pV1 = VTh + (size_t)r1 * VSTRIDE + c0 * 8;
    const float* pB0 = Bias + ((size_t)(blockIdx.y*8 + w*2 + 0) * NJT) * 1024 + quad*64 + l15*4;
    const float* pB1 = Bias + ((size_t)(blockIdx.y*8 + w*2 + 1) * NJT) * 1024 + quad*64 + l15*4;

    // Q fragments (B-operand), 2 x 16 query rows per wave; queries = keys.
    bf16x8 qf[2][2];
    #pragma unroll
    for (int qh = 0; qh < 2; ++qh) {
        int row = q0 + w*32 + qh*16 + l15;      // < 1152, pad rows are zero
        #pragma unroll
        for (int ks = 0; ks < 2; ++ks)
            qf[qh][ks] = *(const bf16x8*)&Kh[(size_t)row * HD + ks*32 + quad*8];
    }

    bf16x8 onesb;
    #pragma unroll
    for (int e = 0; e < 8; ++e) onesb[e] = (bf16)1.0f;

    f32x4 Oacc[2][4] = {};
    f32x4 Lacc[2] = {};
    const int sPr0 = (w*32 + l15) * 64;

    uint4 kva, kvb, vva, vvb;
    f32x4 bpA[2][4], bpB[2][4];   // named bias banks (compile-time indexed)

#define PREFETCH_KV() do { \
        kva = *(const uint4*)pK0; kvb = *(const uint4*)pK1; \
        vva = *(const uint4*)pV0; vvb = *(const uint4*)pV1; \
        pK0 += 64*HD; pK1 += 64*HD; pV0 += 64; pV1 += 64; \
    } while (0)

#define PREFETCH_B(BANK) do { \
        _Pragma("unroll") \
        for (int kt = 0; kt < 4; ++kt) { \
            BANK[0][kt] = *(const f32x4*)(pB0 + kt*256); \
            BANK[1][kt] = *(const f32x4*)(pB1 + kt*256); \
        } \
        pB0 += 1024; pB1 += 1024; \
    } while (0)

#define ITER(CUR, ACC, NEXT) do { \
        *(uint4*)&sK[CUR][dk0] = kva; *(uint4*)&sK[CUR][dk1] = kvb; \
        *(uint4*)&sVT[CUR][dk0] = vva; *(uint4*)&sVT[CUR][dk1] = vvb; \
        PREFETCH_KV(); \
        PREFETCH_B(NEXT); \
        bar(); \
        _Pragma("unroll") \
        for (int ks = 0; ks < 2; ++ks) { \
            bf16x8 af[4]; \
            _Pragma("unroll") \
            for (int kt = 0; kt < 4; ++kt) \
                af[kt] = *(const bf16x8*)&sK[CUR][(kt*16 + l15)*64 + (((ks*4 + quad) ^ sw) << 3)]; \
            __builtin_amdgcn_s_setprio(1); \
            _Pragma("unroll") \
            for (int qh = 0; qh < 2; ++qh) \
                _Pragma("unroll") \
                for (int kt = 0; kt < 4; ++kt) \
                    ACC[qh][kt] = __builtin_amdgcn_mfma_f32_16x16x32_bf16( \
                        af[kt], qf[qh][ks], ACC[qh][kt], 0, 0, 0); \
            __builtin_amdgcn_s_setprio(0); \
        } \
        _Pragma("unroll") \
        for (int qh = 0; qh < 2; ++qh) \
            _Pragma("unroll") \
            for (int kt = 0; kt < 4; ++kt) { \
                float p0 = __builtin_exp2f(ACC[qh][kt][0]); \
                float p1 = __builtin_exp2f(ACC[qh][kt][1]); \
                float p2 = __builtin_exp2f(ACC[qh][kt][2]); \
                float p3 = __builtin_exp2f(ACC[qh][kt][3]); \
                bf16x4 pv = { (bf16)p0, (bf16)p1, (bf16)p2, (bf16)p3 }; \
                int g = (kt*2 + (quad >> 1)) ^ sw; \
                *(bf16x4*)&sP[sPr0 + qh*1024 + g*8 + (quad & 1)*4] = pv; \
            } \
        _Pragma("unroll") \
        for (int ks = 0; ks < 2; ++ks) { \
            bf16x8 bv[4]; \
            _Pragma("unroll") \
            for (int dt = 0; dt < 4; ++dt) \
                bv[dt] = *(const bf16x8*)&sVT[CUR][(dt*16 + l15)*64 + (((ks*4 + quad) ^ sw) << 3)]; \
            __builtin_amdgcn_s_setprio(1); \
            _Pragma("unroll") \
            for (int qh = 0; qh < 2; ++qh) { \
                bf16x8 ap = *(const bf16x8*)&sP[sPr0 + qh*1024 + (((ks*4 + quad) ^ sw) * 8)]; \
                _Pragma("unroll") \
                for (int dt = 0; dt < 4; ++dt) \
                    Oacc[qh][dt] = __builtin_amdgcn_mfma_f32_16x16x32_bf16( \
                        ap, bv[dt], Oacc[qh][dt], 0, 0, 0); \
                Lacc[qh] = __builtin_amdgcn_mfma_f32_16x16x32_bf16( \
                    ap, onesb, Lacc[qh], 0, 0, 0); \
            } \
            __builtin_amdgcn_s_setprio(0); \
        } \
    } while (0)

    PREFETCH_KV();        // tile 0 K/V
    PREFETCH_B(bpA);      // tile 0 bias -> bank A
    ITER(0, bpA, bpB);    // jt 0
    #pragma unroll 1
    for (int it = 0; it < (NJT - 1) / 2; ++it) {   // jt 1..16 as 8 pairs
        ITER(1, bpB, bpA);
        ITER(0, bpA, bpB);
    }
#undef ITER
#undef PREFETCH_KV
#undef PREFETCH_B

    // epilogue: Lacc holds per-row sums (rows quad*4+r) lane-locally
    #pragma unroll
    for (int qh = 0; qh < 2; ++qh)
        #pragma unroll
        for (int r = 0; r < 4; ++r) {
            int g = q0 + w*32 + qh*16 + quad*4 + r;
            if (g >= NSEQ) continue;
            float inv = 1.f / Lacc[qh][r];
            size_t base = ((size_t)(b * NSEQ) + g) * CDIM + h * HD;
            #pragma unroll
            for (int dt = 0; dt < 4; ++dt)
                Hout[base + dt*16 + l15] = (bf16)(Oacc[qh][dt][r] * inv);
        }
}

extern "C" void kernel_launch(void* const* d_in, const int* in_sizes, int n_in,
                              void* d_out, int out_size, void* d_ws, size_t ws_size,
                              hipStream_t stream) {
    const float* x      = (const float*)d_in[0];
    const float* qkv_w  = (const float*)d_in[1];
    const float* qkv_b  = (const float*)d_in[2];
    const float* proj_w = (const float*)d_in[3];
    const float* proj_b = (const float*)d_in[4];
    float* out = (float*)d_out;

    char* ws = (char*)d_ws;
    const size_t XBF_BYTES   = (size_t)MROWS * CDIM * 2;                    // 12.68 MB
    const size_t WKV_BYTES   = (size_t)2 * CDIM * CDIM * 2;                 //  2.36 MB
    const size_t PW_BYTES    = (size_t)CDIM * CDIM * 2;                     //  1.18 MB
    const size_t BIAS_BYTES  = (size_t)NQ16 * NJT * 1024 * 4;               //  5.01 MB
    const size_t KBF_BYTES   = (size_t)BATCH * NHEADS * KSTRIDE * HD * 2;   // 14.16 MB

    bf16*  x_bf   = (bf16*)ws;
    bf16*  wkv_bf = (bf16*)(ws + XBF_BYTES);
    bf16*  pw_bf  = (bf16*)(ws + XBF_BYTES + WKV_BYTES);
    float* bias_t = (float*)(ws + XBF_BYTES + WKV_BYTES + PW_BYTES);
    bf16*  k_bf   = (bf16*)(ws + XBF_BYTES + WKV_BYTES + PW_BYTES + BIAS_BYTES);
    bf16*  vt_bf  = (bf16*)(ws + XBF_BYTES + WKV_BYTES + PW_BYTES + BIAS_BYTES + KBF_BYTES);
    // bias placed before k_bf so the harmless tile-17 bias over-read lands in k_bf

    // fused prep: f32 fragment-linear bias + all casts + K/V^T pad zeroing
    {
        int total = NQ16 * NJT * 1024 + MROWS * CDIM / 4
                  + 2 * CDIM * CDIM / 4 + CDIM * CDIM / 4
                  + BATCH * NHEADS * 120 * 8 + BATCH * NHEADS * 64 * 15;
        prep_kernel<<<dim3((total + 255) / 256), dim3(256), 0, stream>>>(
            x, qkv_w + (size_t)CDIM * CDIM, proj_w, x_bf, wkv_bf, pw_bf, bias_t,
            k_bf, vt_bf);
    }

    // qkv GEMM (k & v only): M=8256, N=1536, K=768 ; writes K' and V^T (padded)
    {
        dim3 grid(1536 / 128, (MROWS + 127) / 128);
        gemm_nt<1><<<grid, dim3(256), 0, stream>>>(x_bf, wkv_bf, qkv_b + CDIM,
                                                   nullptr, k_bf, vt_bf,
                                                   MROWS, 1536, CDIM);
    }

    // attention -> hidden (reuse x_bf buffer); grid (bh, qtile)
    {
        dim3 grid(BATCH * NHEADS, (NSEQ + 127) / 128);
        attn_kernel<<<grid, dim3(256), 0, stream>>>(k_bf, vt_bf, bias_t, x_bf);
    }

    // proj GEMM: out = hidden @ proj_w^T + proj_b, fp32 out
    {
        dim3 grid(CDIM / 128, (MROWS + 127) / 128);
        gemm_nt<0><<<grid, dim3(256), 0, stream>>>(x_bf, pw_bf, proj_b,
                                                   out, nullptr, nullptr,
                                                   MROWS, CDIM, CDIM);
    }
}